// Round 14
// baseline (153.201 us; speedup 1.0000x reference)
//
#include <hip/hip_runtime.h>
#include <math.h>

#define HW (128*128)

typedef short short8 __attribute__((ext_vector_type(8)));
typedef float floatx4 __attribute__((ext_vector_type(4)));
typedef unsigned int uintx4 __attribute__((ext_vector_type(4)));
typedef _Float16 half2v __attribute__((ext_vector_type(2)));
typedef _Float16 half8v __attribute__((ext_vector_type(8)));

#define MFMA(a,b,c)   __builtin_amdgcn_mfma_f32_16x16x32_bf16((a),(b),(c),0,0,0)
#define MFMA16(a,b,c) __builtin_amdgcn_mfma_f32_16x16x32_f16((a),(b),(c),0,0,0)

union V16 { uintx4 u; half2v h2[4]; half8v h8; _Float16 h[8]; };

// ---------------- workspace layout ----------------
#define WT3_ELEMS   (9*3*4*64*8)         // [kk][ks][quad][o][i], c=ks*32+quad*8+i
#define WMTA_ELEMS  (19*2*4*16*8)        // [kt][n][quad][m15][i]
#define WMT_ELEMS   (594*27)             // MID tier fp32
#define TIN_BYTES   ((size_t)8*HW*64*2)  // 16 MB
#define WT3_OFF     TIN_BYTES
#define WMTA_OFF    (WT3_OFF + (size_t)WT3_ELEMS*2)
#define WS_FULL     (WMTA_OFF + (size_t)WMTA_ELEMS*2)
#define WS_MID      ((size_t)WT3_ELEMS*2 + (size_t)WMT_ELEMS*4)

static __device__ __forceinline__ unsigned short f2bf(float x) {
    unsigned u = __float_as_uint(x);
    unsigned r = u + 0x7FFFu + ((u >> 16) & 1u);
    return (unsigned short)(r >> 16);
}

static __device__ __forceinline__ unsigned cvt_pk_bf16(float lo, float hi) {
    unsigned r;
    asm("v_cvt_pk_bf16_f32 %0, %1, %2" : "=v"(r) : "v"(lo), "v"(hi));
    return r;
}

// ---------------- prep: fp16 weights (FULL tier) ----------------
__global__ __launch_bounds__(256) void prep_w16(
    const float* __restrict__ weight, const float* __restrict__ w_om,
    _Float16* __restrict__ wt3, _Float16* __restrict__ wmtA)
{
    int t = blockIdx.x * 256 + threadIdx.x;
    if (t < WT3_ELEMS) {
        int i = t & 7;  int u = t >> 3;
        int o = u & 63; u >>= 6;
        int quad = u & 3; u >>= 2;
        int ks = u % 3, kk = u / 3;
        int c = ks * 32 + quad * 8 + i;
        float v = (c < 66) ? weight[o * 594 + c * 9 + kk] : 0.0f;
        wt3[t] = (_Float16)v;
    } else if (t < WT3_ELEMS + WMTA_ELEMS) {
        int t2 = t - WT3_ELEMS;
        int i = t2 & 7;  int u = t2 >> 3;
        int m15 = u & 15; u >>= 4;
        int quad = u & 3; u >>= 2;
        int n = u & 1;    int kt = u >> 1;
        int o = 16 * n + m15;
        float v = 0.0f;
        if (o < 27) {
            if (kt < 18) {
                int j = kt >> 1, c = (kt & 1) * 32 + quad * 8 + i;
                v = w_om[o * 594 + c * 9 + j];
            } else {
                int q = quad * 8 + i;
                if (q < 18) {
                    int j = q >> 1, c = 64 + (q & 1);
                    v = w_om[o * 594 + c * 9 + j];
                }
            }
        }
        wmtA[t2] = (_Float16)v;
    }
}

// ---------------- prep: NCHW fp32 -> NHWC fp16 transpose (vectorized) -------
__global__ __launch_bounds__(256) void prep_t(
    const float* __restrict__ in, _Float16* __restrict__ t_out)
{
    __shared__ float s[64][129];
    const int y = blockIdx.x, b = blockIdx.y;
    const int tid = threadIdx.x, lane = tid & 63, w = tid >> 6;
    const float* src = in + (size_t)b * 64 * HW + y * 128;
#pragma unroll
    for (int i = 0; i < 16; ++i) {
        int c = w * 16 + i;
        s[c][lane]      = src[(size_t)c * HW + lane];
        s[c][lane + 64] = src[(size_t)c * HW + lane + 64];
    }
    __syncthreads();
    _Float16* dst = t_out + ((size_t)b * HW + (size_t)y * 128) * 64;
    // R14: 16B/lane packed stores (was 2B scalar, 8x under-vectorized)
#pragma unroll
    for (int it = 0; it < 4; ++it) {
        int idx = it * 256 + tid;        // 0..1023
        int x = idx >> 3, g = idx & 7;   // pixel x, channel-group g
        V16 v;
#pragma unroll
        for (int j = 0; j < 8; ++j)
            v.h[j] = (_Float16)s[g * 8 + j][x];
        *(uintx4*)&dst[(size_t)x * 64 + g * 8] = v.u;
    }
}

// ---------------- prep: weights (bf16+fp32, MID tier) ----------------
__global__ __launch_bounds__(256) void prep_w(
    const float* __restrict__ weight, const float* __restrict__ w_om,
    unsigned short* __restrict__ wt3, float* __restrict__ wmt)
{
    int t = blockIdx.x * 256 + threadIdx.x;
    if (t < WT3_ELEMS) {
        int i = t & 7;  int u = t >> 3;
        int o = u & 63; u >>= 6;
        int quad = u & 3; u >>= 2;
        int ks = u % 3, kk = u / 3;
        int c = ks * 32 + quad * 8 + i;
        float v = (c < 66) ? weight[o * 594 + c * 9 + kk] : 0.0f;
        wt3[t] = f2bf(v);
    } else if (t < WT3_ELEMS + WMT_ELEMS) {
        int t2 = t - WT3_ELEMS;
        int oc = t2 % 27, ck = t2 / 27;
        wmt[t2] = w_om[oc * 594 + ck];
    }
}

// Round 2:  XCD-pinning remap (FETCH 268->18.5MB, verified).
// Round 6:  NHWC fp16 shadow input (274 -> 214us).
// Round 7:  Phase A on matrix cores (214 -> 171us).
// Round 10: spill fix (171 -> 119.6us).
// Round 13: LDS gather tile (119.6 -> 69.2us; theory confirmed: VALUBusy
//   18->36%, MfmaUtil 6.5->11.3%).
// Round 14: LDS DIET -> 3 blocks/CU. Occupancy was 19.4% (58.9KB -> 2
//   blocks/CU, 2 waves/SIMD): one wave's ds_read stalls can't hide behind
//   another's VALU. Cuts: (a) Phase-B offsets/mask stored fp16 in LDS
//   (6912->3456B; idx/mask OUTPUTS stay fp32-exact; fp16 rounding of the
//   Phase-B copy adds ~1e-3 << 0.06 tol); (b) s_om 32x65 -> 27x65 (only 27
//   oc exist; writes to rows>=27 guarded off); (c) final epilogue in 4
//   rounds of 16 channels. Total 53996B <= 54613 -> 3 blocks/CU (12 waves).
__global__ __launch_bounds__(256, 2) void dcn_hybrid13(
    const _Float16* __restrict__ t_in,
    const _Float16* __restrict__ wt3h,
    const _Float16* __restrict__ wmtA,
    const float* __restrict__ bias,
    const float* __restrict__ b_om,
    float* __restrict__ out)
{
    // tile line (r,c) = image (clamp(ho-2+r), clamp(wo0-2+c)), 64ch fp16 =
    // 128B = 8 chunks of 16B; chunk k stored at slot k ^ (c&7).
    __shared__ __align__(16) unsigned short s_tile[5 * 68 * 64];       // 43520 B
    __shared__ float s_om[27 * 65];                                    // 7020 B
    __shared__ _Float16 s_offh16[9 * 64], s_offw16[9 * 64], s_mask16[9 * 64]; // 3456 B

    const int tid  = threadIdx.x;
    const int lane = tid & 63;
    const int w    = tid >> 6;
    const int wu   = __builtin_amdgcn_readfirstlane(w);
    const int m15  = lane & 15;
    const int quad = lane >> 4;

    // ---- XCD-pinning remap
    const int L   = blockIdx.x + 2 * (blockIdx.y + 128 * blockIdx.z);
    const int b   = L & 7;
    const int r   = L >> 3;
    const int ho  = r >> 1;
    const int wo0 = (r & 1) * 64;

    const float invH = 1.0f / 128.0f;

    const int pixL = wu * 16 + m15;
    const int wob  = wo0 + pixL;

    const _Float16* tinb = t_in + (size_t)b * HW * 64;
    const _Float16* tinq = tinb + quad * 8;     // global-fallback base

    // ---------------- stage the tile (coalesced, once) ----------------
    for (int Lt = tid; Lt < 340; Lt += 256) {
        int rt = Lt / 68, ct = Lt - rt * 68;
        int gy = min(max(ho - 2 + rt, 0), 127);
        int gx = min(max(wo0 - 2 + ct, 0), 127);
        const uintx4* src = (const uintx4*)(tinb + ((size_t)gy * 128 + gx) * 64);
        uintx4* dst = (uintx4*)&s_tile[(size_t)Lt * 64];
        int sw = ct & 7;
#pragma unroll
        for (int k = 0; k < 8; ++k)
            dst[k ^ sw] = src[k];
    }

    // tile read: logical 16B chunk q (0..7) of tile line (rt, ct)
    auto tileread = [&](int rt, int ct, int q) -> uintx4 {
        return *(const uintx4*)&s_tile[(((rt * 68 + ct) << 3) + (q ^ (ct & 7))) << 3];
    };

    // ---- 9 fixed-tap tile coords / validity for pixel (ho, wob)
    int   tr9[9], tc9[9];
    float ok9[9];
#pragma unroll
    for (int j = 0; j < 9; ++j) {
        int y = ho - 1 + j / 3;
        int x = wob - 1 + j % 3;
        bool ok = ((unsigned)y < 128u) && ((unsigned)x < 128u);
        int yc = min(max(y, 0), 127), xc = min(max(x, 0), 127);
        tr9[j] = yc - (ho - 2);          // in [0,5)
        tc9[j] = xc - (wo0 - 2);         // in [0,68)
        ok9[j] = ok ? 1.0f : 0.0f;
    }
    __syncthreads();   // tile staged

    // ---------------- Phase A: offset conv via f16 MFMA (tile reads) ------
    floatx4 a0 = (floatx4){0.f, 0.f, 0.f, 0.f};
    floatx4 a1 = (floatx4){0.f, 0.f, 0.f, 0.f};

#pragma unroll
    for (int j = 0; j < 9; ++j) {
        _Float16 okh = (_Float16)ok9[j];
        half2v okh2 = {okh, okh};
#pragma unroll
        for (int h = 0; h < 2; ++h) {
            V16 bb;
            bb.u = tileread(tr9[j], tc9[j], 4 * h + quad);
#pragma unroll
            for (int rr = 0; rr < 4; ++rr) bb.h2[rr] = bb.h2[rr] * okh2;
            const int kt = j * 2 + h;
            const _Float16* ap = wmtA + (size_t)((kt * 2) * 4 + quad) * 128 + m15 * 8;
            half8v A0 = *(const half8v*)ap;
            half8v A1 = *(const half8v*)(ap + 512);
            a0 = MFMA16(A0, bb.h8, a0);
            a1 = MFMA16(A1, bb.h8, a1);
        }
    }
    {   // coord K-tile (kt=18)
        V16 bb;
#pragma unroll
        for (int rr = 0; rr < 4; ++rr) {
            float ve = 0.f, vo = 0.f;
            int j = quad * 4 + rr;
            if (j < 9) {
                int y = ho - 1 + j / 3;
                int x = wob - 1 + j % 3;
                bool ok = ((unsigned)y < 128u) && ((unsigned)x < 128u);
                ve = ok ? y * invH : 0.f;
                vo = ok ? (x * invH - 0.5f) : 0.f;
            }
            bb.h2[rr] = (half2v){(_Float16)ve, (_Float16)vo};
        }
        const _Float16* ap = wmtA + (size_t)((18 * 2) * 4 + quad) * 128 + m15 * 8;
        half8v A0 = *(const half8v*)ap;
        half8v A1 = *(const half8v*)(ap + 512);
        a0 = MFMA16(A0, bb.h8, a0);
        a1 = MFMA16(A1, bb.h8, a1);
    }

    // stage om to LDS: s_om[oc][pix], 27 rows only (rows >= 27 are padding)
#pragma unroll
    for (int rr = 0; rr < 4; ++rr) {
        s_om[(quad * 4 + rr) * 65 + pixL] = a0[rr];
        if (quad * 4 + rr < 11)
            s_om[(16 + quad * 4 + rr) * 65 + pixL] = a1[rr];
    }
    __syncthreads();

    // ---- idx/mask epilogue (nt stores, fp32) + fp16 offsets/mask into LDS
    {
        float* out_idx = out + (size_t)8 * 64 * HW;
        float* out_msk = out_idx + (size_t)8 * 18 * HW;
        const int wo = wo0 + lane;
        const int p  = ho * 128 + wo;
        const float hg = ho * invH;
        const float wg = wo * invH - 0.5f;
        int oc0 = wu * 7;
        int noc = (wu == 3) ? 6 : 7;
        for (int t = 0; t < noc; ++t) {
            int oc = oc0 + t;
            float s = b_om[oc] + s_om[oc * 65 + lane];
            if (oc < 9) {
                __builtin_nontemporal_store(hg + (float)(oc / 3 - 1) + s,
                    &out_idx[((size_t)b * 18 + oc) * HW + p]);
                if (oc & 1) s_offw16[(oc >> 1) * 64 + lane] = (_Float16)s;
                else        s_offh16[(oc >> 1) * 64 + lane] = (_Float16)s;
            } else if (oc < 18) {
                __builtin_nontemporal_store(wg + (float)((oc - 9) % 3 - 1) + s,
                    &out_idx[((size_t)b * 18 + oc) * HW + p]);
                if (oc & 1) s_offw16[(oc >> 1) * 64 + lane] = (_Float16)s;
                else        s_offh16[(oc >> 1) * 64 + lane] = (_Float16)s;
            } else {
                float mkv = 1.0f / (1.0f + __expf(-s));
                __builtin_nontemporal_store(mkv,
                    &out_msk[((size_t)b * 9 + (oc - 18)) * HW + p]);
                s_mask16[(oc - 18) * 64 + lane] = (_Float16)mkv;
            }
        }
    }
    __syncthreads();   // offsets/mask ready

    // ---------------- Phase B: tile ds_reads + f16 MFMA -------------------
    floatx4 acc[4];
#pragma unroll
    for (int t = 0; t < 4; ++t) acc[t] = (floatx4){0.f, 0.f, 0.f, 0.f};

    const int hom1 = ho - 1;

#pragma unroll
    for (int kk = 0; kk < 9; ++kk) {
        float offh = (float)s_offh16[kk * 64 + pixL];
        float offw = (float)s_offw16[kk * 64 + pixL];
        float mval = (float)s_mask16[kk * 64 + pixL];

        float ph = offh + (float)(kk / 3) + (float)hom1;
        float pw = offw + (float)(kk % 3) + (float)(wob - 1);
        float h0f = floorf(ph), w0f = floorf(pw);
        int h0 = (int)h0f, w0 = (int)w0f;
        int h1 = h0 + 1, w1 = w0 + 1;
        float lh = ph - h0f, lw = pw - w0f;
        float hh = 1.0f - lh, hwp = 1.0f - lw;
        bool okh0 = (unsigned)h0 < 128u, okh1 = (unsigned)h1 < 128u;
        bool okw0 = (unsigned)w0 < 128u, okw1 = (unsigned)w1 < 128u;
        float w00 = (okh0 && okw0) ? hh * hwp * mval : 0.0f;
        float w01 = (okh0 && okw1) ? hh * lw  * mval : 0.0f;
        float w10 = (okh1 && okw0) ? lh * hwp * mval : 0.0f;
        float w11 = (okh1 && okw1) ? lh * lw  * mval : 0.0f;
        int h0c = min(max(h0, 0), 127), h1c = min(max(h1, 0), 127);
        int w0c = min(max(w0, 0), 127), w1c = min(max(w1, 0), 127);

        int r0 = h0c - (ho - 2), r1 = h1c - (ho - 2);
        int c0 = w0c - (wo0 - 2), c1 = w1c - (wo0 - 2);
        bool intile = ((unsigned)r0 < 5u) && ((unsigned)r1 < 5u)
                   && ((unsigned)c0 < 68u) && ((unsigned)c1 < 68u);

        V16 A00, A01, A10, A11, B00, B01, B10, B11;
        if (__all(intile)) {
            A00.u = tileread(r0, c0, quad);     A01.u = tileread(r0, c1, quad);
            A10.u = tileread(r1, c0, quad);     A11.u = tileread(r1, c1, quad);
            B00.u = tileread(r0, c0, quad + 4); B01.u = tileread(r0, c1, quad + 4);
            B10.u = tileread(r1, c0, quad + 4); B11.u = tileread(r1, c1, quad + 4);
        } else {
            int o00 = h0c * 128 + w0c, o01 = h0c * 128 + w1c;
            int o10 = h1c * 128 + w0c, o11 = h1c * 128 + w1c;
            A00.u = *(const uintx4*)(tinq + (size_t)o00 * 64);
            A01.u = *(const uintx4*)(tinq + (size_t)o01 * 64);
            A10.u = *(const uintx4*)(tinq + (size_t)o10 * 64);
            A11.u = *(const uintx4*)(tinq + (size_t)o11 * 64);
            B00.u = *(const uintx4*)(tinq + (size_t)o00 * 64 + 32);
            B01.u = *(const uintx4*)(tinq + (size_t)o01 * 64 + 32);
            B10.u = *(const uintx4*)(tinq + (size_t)o10 * 64 + 32);
            B11.u = *(const uintx4*)(tinq + (size_t)o11 * 64 + 32);
        }

        _Float16 h00 = (_Float16)w00, h01 = (_Float16)w01;
        _Float16 h10 = (_Float16)w10, h11 = (_Float16)w11;
        half2v W00 = {h00, h00}, W01 = {h01, h01};
        half2v W10 = {h10, h10}, W11 = {h11, h11};

        V16 b0, b1, b2;
#pragma unroll
        for (int rr = 0; rr < 4; ++rr) {
            b0.h2[rr] = A00.h2[rr] * W00 + A01.h2[rr] * W01
                      + A10.h2[rr] * W10 + A11.h2[rr] * W11;
            b1.h2[rr] = B00.h2[rr] * W00 + B01.h2[rr] * W01
                      + B10.h2[rr] * W10 + B11.h2[rr] * W11;
        }
        float c64 = (w00 + w01) * (h0c * invH) + (w10 + w11) * (h1c * invH);
        float c65 = (w00 + w10) * (w0c * invH - 0.5f) + (w01 + w11) * (w1c * invH - 0.5f);
        b2.u = (uintx4){0u, 0u, 0u, 0u};
        if (quad == 0) b2.h2[0] = (half2v){(_Float16)c64, (_Float16)c65};

        const _Float16* w0p = wt3h + (size_t)(kk * 3) * 2048 + quad * 512;
        const _Float16* w1p = w0p + 2048;
        const _Float16* w2p = w0p + 4096;
#pragma unroll
        for (int t = 0; t < 4; ++t) {
            int o8 = (16 * t + m15) * 8;
            half8v A0 = *(const half8v*)&w0p[o8];
            half8v A1 = *(const half8v*)&w1p[o8];
            half8v A2 = *(const half8v*)&w2p[o8];
            acc[t] = MFMA16(A0, b0.h8, acc[t]);
            acc[t] = MFMA16(A1, b1.h8, acc[t]);
            acc[t] = MFMA16(A2, b2.h8, acc[t]);
        }
    }

    // ---------- epilogue: LDS redistribute (4 x 16 ch) -> full-line nt stores
    // acc[t][rr] holds o = 16t + quad*4 + rr for pixel pixL (verified R7).
    {
        const size_t rowbase = (size_t)b * 64 * HW + (size_t)ho * 128 + wo0;
#pragma unroll
        for (int t = 0; t < 4; ++t) {
            __syncthreads();   // prev round's reads (or Phase B) done
#pragma unroll
            for (int rr = 0; rr < 4; ++rr)
                s_om[(quad * 4 + rr) * 65 + pixL] = acc[t][rr];
            __syncthreads();
#pragma unroll
            for (int k = 0; k < 4; ++k) {
                int o = 16 * t + wu * 4 + k;
                float v = s_om[(wu * 4 + k) * 65 + lane] + bias[o];
                __builtin_nontemporal_store(v, &out[(size_t)o * HW + rowbase + lane]);
            }
        }
    }
}

// ---------------- MID tier: R5 kernel (verified), bf16 MFMA ----------------
__global__ __launch_bounds__(256, 4) void dcn_hybrid7(
    const float* __restrict__ input,
    const unsigned short* __restrict__ wt3,
    const float* __restrict__ bias,
    const float* __restrict__ wmt,
    const float* __restrict__ b_om,
    float* __restrict__ out)
{
    __shared__ float s_red[4 * 27 * 64];
    __shared__ float s_offh[9 * 64], s_offw[9 * 64], s_maskf[9 * 64];

    const int tid  = threadIdx.x;
    const int lane = tid & 63;
    const int w    = tid >> 6;
    const int wu   = __builtin_amdgcn_readfirstlane(w);
    const int m15  = lane & 15;
    const int quad = lane >> 4;

    const int L   = blockIdx.x + 2 * (blockIdx.y + 128 * blockIdx.z);
    const int b   = L & 7;
    const int r   = L >> 3;
    const int ho  = r >> 1;
    const int wo0 = (r & 1) * 64;

    const int wo  = wo0 + lane;
    const int p   = ho * 128 + wo;
    const float invH = 1.0f / 128.0f;

    const float* inb = input + (size_t)b * 64 * HW;

    int   a9[9];
    float okf[9], vy[9], vx[9];
#pragma unroll
    for (int j = 0; j < 9; ++j) {
        int y = ho - 1 + j / 3;
        int x = wo - 1 + j % 3;
        bool ok = ((unsigned)y < 128u) && ((unsigned)x < 128u);
        int yc = min(max(y, 0), 127), xc = min(max(x, 0), 127);
        a9[j]  = yc * 128 + xc;
        okf[j] = ok ? 1.0f : 0.0f;
        vy[j]  = ok ? y * invH : 0.0f;
        vx[j]  = ok ? (x * invH - 0.5f) : 0.0f;
    }

    const int nc = (wu < 2) ? 17 : 16;

    float om_part[27];
#pragma unroll
    for (int oc = 0; oc < 27; ++oc) om_part[oc] = 0.0f;

    {
        float va[9], vb[9];
        {
            const float* pc = inb + wu * HW;
#pragma unroll
            for (int j = 0; j < 9; ++j) va[j] = pc[a9[j]] * okf[j];
        }
        for (int i = 0; i < nc; ++i) {
            int c = wu + 4 * i;
            if (i + 1 < nc) {
                int cn = c + 4;
                if (cn < 64) {
                    const float* pc = inb + cn * HW;
#pragma unroll
                    for (int j = 0; j < 9; ++j) vb[j] = pc[a9[j]] * okf[j];
                } else if (cn == 64) {
#pragma unroll
                    for (int j = 0; j < 9; ++j) vb[j] = vy[j];
                } else {
#pragma unroll
                    for (int j = 0; j < 9; ++j) vb[j] = vx[j];
                }
            }
#pragma unroll
            for (int j = 0; j < 9; ++j) {
                const float* wp = wmt + (c * 9 + j) * 27;
#pragma unroll
                for (int oc = 0; oc < 27; ++oc)
                    om_part[oc] = fmaf(va[j], wp[oc], om_part[oc]);
            }
#pragma unroll
            for (int j = 0; j < 9; ++j) va[j] = vb[j];
        }
    }
#pragma unroll
    for (int oc = 0; oc < 27; ++oc)
        s_red[(w * 27 + oc) * 64 + lane] = om_part[oc];
    __syncthreads();

    {
        float* out_idx = out + (size_t)8 * 64 * HW;
        float* out_msk = out_idx + (size_t)8 * 18 * HW;
        const float hg = ho * invH;
        const float wg = wo * invH - 0.5f;
        int oc0 = wu * 7;
        int noc = (wu == 3) ? 6 : 7;
        for (int t = 0; t < noc; ++t) {
            int oc = oc0 + t;
            float s = b_om[oc]
                    + s_red[(0 * 27 + oc) * 64 + lane]
                    + s_red[(1 * 27 + oc) * 64 + lane]
                    + s_red[(2 * 27 + oc) * 64 + lane]
                    + s_red[(3 * 27 + oc) * 64 + lane];
            if (oc < 9) {
                out_idx[((size_t)b * 18 + oc) * HW + p] = hg + (float)(oc / 3 - 1) + s;
                if (oc & 1) s_offw[(oc >> 1) * 64 + lane] = s;
                else        s_offh[(oc >> 1) * 64 + lane] = s;
            } else if (oc < 18) {
                out_idx[((size_t)b * 18 + oc) * HW + p] = wg + (float)((oc - 9) % 3 - 1) + s;
                if (oc & 1) s_offw[(oc >> 1) * 64 + lane] = s;
                else        s_offh[(oc >> 1) * 64 + lane] = s;
            } else {
                float mkv = 1.0f / (1.0f + __expf(-s));
                out_msk[((size_t)b * 9 + (oc - 18)) * HW + p] = mkv;
                s_maskf[(oc - 18) * 64 + lane] = mkv;
            }
        }
    }
    __syncthreads();

    const int pixL = wu * 16 + m15;
    const int wob  = wo0 + pixL;
    const int hom1 = ho - 1;

    floatx4 acc[4];
#pragma unroll
    for (int t = 0; t < 4; ++t) acc[t] = (floatx4){0.f, 0.f, 0.f, 0.f};

    const float* base0 = inb + (size_t)(quad * 8) * HW;
    const float* base1 = base0 + (size_t)32 * HW;

#pragma unroll
    for (int kk = 0; kk < 9; ++kk) {
        float offh = s_offh[kk * 64 + pixL];
        float offw = s_offw[kk * 64 + pixL];
        float mval = s_maskf[kk * 64 + pixL];

        float ph = offh + (float)(kk / 3) + (float)hom1;
        float pw = offw + (float)(kk % 3) + (float)(wob - 1);
        float h0f = floorf(ph), w0f = floorf(pw);
        int h0 = (int)h0f, w0 = (int)w0f;
        int h1 = h0 + 1, w1 = w0 + 1;
        float lh = ph - h0f, lw = pw - w0f;
        float hh = 1.0f - lh, hwp = 1.0f - lw;
        bool okh0 = (unsigned)h0 < 128u, okh1 = (unsigned)h1 < 128u;
        bool okw0 = (unsigned)w0 < 128u, okw1 = (unsigned)w1 < 128u;
        float w00 = (okh0 && okw0) ? hh * hwp * mval : 0.0f;
        float w01 = (okh0 && okw1) ? hh * lw  * mval : 0.0f;
        float w10 = (okh1 && okw0) ? lh * hwp * mval : 0.0f;
        float w11 = (okh1 && okw1) ? lh * lw  * mval : 0.0f;
        int h0c = min(max(h0, 0), 127), h1c = min(max(h1, 0), 127);
        int w0c = min(max(w0, 0), 127), w1c = min(max(w1, 0), 127);
        int o00 = h0c * 128 + w0c, o01 = h0c * 128 + w1c;
        int o10 = h1c * 128 + w0c, o11 = h1c * 128 + w1c;

        unsigned pk0[4], pk1[4];
#pragma unroll
        for (int j = 0; j < 4; ++j) {
            const float* pa = base0 + (size_t)(2 * j) * HW;
            const float* pb = pa + HW;
            float ca = w00 * pa[o00] + w01 * pa[o01] + w10 * pa[o10] + w11 * pa[o11];
            float cb = w00 * pb[o00] + w01 * pb[o01] + w10 * pb[o10] + w11 * pb[o11];
            pk0[j] = cvt_pk_bf16(ca, cb);
            const float* pa1 = base1 + (size_t)(2 * j) * HW;
            const float* pb1 = pa1 + HW;
            float ca1 = w00 * pa1[o00] + w01 * pa1[o01] + w10 * pa1[o10] + w11 * pa1[o11];
            float cb1 = w00 * pb1[o00] + w01 * pb1[o01] + w10 * pb1[o10] + w11 * pb1[o11];
            pk1[j] = cvt_pk_bf16(ca1, cb1);
        }
        union { uintx4 u; short8 s; } b0, b1, b2;
        b0.u = (uintx4){pk0[0], pk0[1], pk0[2], pk0[3]};
        b1.u = (uintx4){pk1[0], pk1[1], pk1[2], pk1[3]};
        float c64 = (w00 + w01) * (h0c * invH) + (w10 + w11) * (h1c * invH);
        float c65 = (w00 + w10) * (w0c * invH - 0.5f) + (w01 + w11) * (w1c * invH - 0.5f);
        unsigned pk2 = (quad == 0) ? cvt_pk_bf16(c64, c65) : 0u;
        b2.u = (uintx4){pk2, 0u, 0u, 0u};

        const unsigned short* w0p = wt3 + (size_t)(kk * 3 + 0) * 2048 + quad * 512;
        const unsigned short* w1p = w0p + 2048;
        const unsigned short* w2p = w0p + 4096;
#pragma unroll
        for (int t = 0; t < 4; ++t) {
            int o8 = (16 * t + m15) * 8;
            short8 A0 = *(const short8*)&w0p[o8];
            short8 A1 = *(const short8*)&w1p[o8];
            short8 A2 = *(const short8*)&w2p[o8];
            acc[t] = MFMA(A0, b0.s, acc[t]);
            acc[t] = MFMA(A1, b1.s, acc[t]);
            acc[t] = MFMA(A2, b2.s, acc[t]);
        }
    }

    {
        size_t pb = (size_t)ho * 128 + wob;
#pragma unroll
        for (int t = 0; t < 4; ++t) {
#pragma unroll
            for (int rr = 0; rr < 4; ++rr) {
                int o = 16 * t + quad * 4 + rr;
                out[((size_t)b * 64 + o) * HW + pb] = acc[t][rr] + bias[o];
            }
        }
    }
}

// ------------------- fallback (no workspace): fp32 baseline -------------------
__global__ __launch_bounds__(256) void dcn_fb(
    const float* __restrict__ input,
    const float* __restrict__ wmain,
    const float* __restrict__ bias,
    const float* __restrict__ wom,
    const float* __restrict__ b_om,
    float* __restrict__ out)
{
    const int wo = blockIdx.x * 64 + threadIdx.x;
    const int ho = blockIdx.y * 4 + threadIdx.y;
    const int b  = blockIdx.z;
    const int p  = ho * 128 + wo;
    const float invH = 1.0f / 128.0f;
    const float* inb = input + (size_t)b * 64 * HW;

    float om[27];
#pragma unroll
    for (int oc = 0; oc < 27; ++oc) om[oc] = b_om[oc];

    for (int c = 0; c < 64; ++c) {
        const float* pc = inb + c * HW;
        float v[9];
#pragma unroll
        for (int kh = 0; kh < 3; ++kh) {
            int y = ho - 1 + kh;
            bool oky = (unsigned)y < 128u;
#pragma unroll
            for (int kw = 0; kw < 3; ++kw) {
                int x = wo - 1 + kw;
                bool ok = oky && ((unsigned)x < 128u);
                v[kh*3+kw] = ok ? pc[y * 128 + x] : 0.0f;
            }
        }
#pragma unroll
        for (int oc = 0; oc < 27; ++oc)
#pragma unroll
            for (int i = 0; i < 9; ++i)
                om[oc] = fmaf(v[i], wom[oc*594 + c*9 + i], om[oc]);
    }
    {
        float v64[9], v65[9];
#pragma unroll
        for (int kh = 0; kh < 3; ++kh) {
            int y = ho - 1 + kh;
            bool oky = (unsigned)y < 128u;
#pragma unroll
            for (int kw = 0; kw < 3; ++kw) {
                int x = wo - 1 + kw;
                bool ok = oky && ((unsigned)x < 128u);
                v64[kh*3+kw] = ok ? y * invH : 0.0f;
                v65[kh*3+kw] = ok ? (x * invH - 0.5f) : 0.0f;
            }
        }
#pragma unroll
        for (int oc = 0; oc < 27; ++oc)
#pragma unroll
            for (int i = 0; i < 9; ++i) {
                om[oc] = fmaf(v64[i], wom[oc*594 + 64*9 + i], om[oc]);
                om[oc] = fmaf(v65[i], wom[oc*594 + 65*9 + i], om[oc]);
            }
    }

    const float hg = ho * invH;
    const float wg = wo * invH - 0.5f;
    float* out_idx = out + (size_t)8 * 64 * HW;
    float* out_msk = out_idx + (size_t)8 * 18 * HW;
#pragma unroll
    for (int cc = 0; cc < 9; ++cc)
        out_idx[((size_t)b*18 + cc)*HW + p] = hg + (float)(cc/3 - 1) + om[cc];
#pragma unroll
    for (int cc = 9; cc < 18; ++cc)
        out_idx[((size_t)b*18 + cc)*HW + p] = wg + (float)((cc-9)%3 - 1) + om[cc];

    float mk[9];
#pragma unroll
    for (int kk = 0; kk < 9; ++kk) {
        mk[kk] = 1.0f / (1.0f + __expf(-om[18+kk]));
        out_msk[((size_t)b*9 + kk)*HW + p] = mk[kk];
    }

    float acc[64];
#pragma unroll
    for (int o = 0; o < 64; ++o) acc[o] = bias[o];

#pragma unroll
    for (int kk = 0; kk < 9; ++kk) {
        float ph = om[2*kk]   + (float)(kk/3) + (float)(ho - 1);
        float pw = om[2*kk+1] + (float)(kk%3) + (float)(wo - 1);
        float h0f = floorf(ph), w0f = floorf(pw);
        int h0 = (int)h0f, w0 = (int)w0f;
        int h1 = h0 + 1, w1 = w0 + 1;
        float lh = ph - h0f, lw = pw - w0f;
        float hh = 1.0f - lh, hwp = 1.0f - lw;
        float m = mk[kk];
        bool okh0 = (unsigned)h0 < 128u, okh1 = (unsigned)h1 < 128u;
        bool okw0 = (unsigned)w0 < 128u, okw1 = (unsigned)w1 < 128u;
        float w00 = (okh0 && okw0) ? hh*hwp*m : 0.0f;
        float w01 = (okh0 && okw1) ? hh*lw*m  : 0.0f;
        float w10 = (okh1 && okw0) ? lh*hwp*m : 0.0f;
        float w11 = (okh1 && okw1) ? lh*lw*m  : 0.0f;
        int h0c = min(max(h0, 0), 127), h1c = min(max(h1, 0), 127);
        int w0c = min(max(w0, 0), 127), w1c = min(max(w1, 0), 127);
        int o00 = h0c*128 + w0c, o01 = h0c*128 + w1c;
        int o10 = h1c*128 + w0c, o11 = h1c*128 + w1c;

        for (int c = 0; c < 64; ++c) {
            const float* pc = inb + c * HW;
            float col = w00*pc[o00] + w01*pc[o01] + w10*pc[o10] + w11*pc[o11];
#pragma unroll
            for (int o = 0; o < 64; ++o)
                acc[o] = fmaf(col, wmain[o*594 + c*9 + kk], acc[o]);
        }
        {
            float y0 = h0c * invH, y1 = h1c * invH;
            float x0 = w0c * invH - 0.5f, x1 = w1c * invH - 0.5f;
            float col64 = (w00 + w01)*y0 + (w10 + w11)*y1;
            float col65 = (w00 + w10)*x0 + (w01 + w11)*x1;
#pragma unroll
            for (int o = 0; o < 64; ++o) {
                acc[o] = fmaf(col64, wmain[o*594 + 64*9 + kk], acc[o]);
                acc[o] = fmaf(col65, wmain[o*594 + 65*9 + kk], acc[o]);
            }
        }
    }

#pragma unroll
    for (int o = 0; o < 64; ++o)
        out[((size_t)b*64 + o)*HW + p] = acc[o];
}

extern "C" void kernel_launch(void* const* d_in, const int* in_sizes, int n_in,
                              void* d_out, int out_size, void* d_ws, size_t ws_size,
                              hipStream_t stream)
{
    const float* input  = (const float*)d_in[0];
    const float* weight = (const float*)d_in[1];
    const float* bias   = (const float*)d_in[2];
    const float* w_om   = (const float*)d_in[3];
    const float* b_om   = (const float*)d_in[4];
    float* out = (float*)d_out;

    if (ws_size >= WS_FULL) {
        _Float16* tin  = (_Float16*)d_ws;
        _Float16* wt3h = (_Float16*)((char*)d_ws + WT3_OFF);
        _Float16* wmtA = (_Float16*)((char*)d_ws + WMTA_OFF);
        int total = WT3_ELEMS + WMTA_ELEMS;
        prep_w16<<<(total + 255) / 256, 256, 0, stream>>>(weight, w_om, wt3h, wmtA);
        prep_t<<<dim3(128, 8), 256, 0, stream>>>(input, tin);
        dim3 grid(2, 128, 8);
        dcn_hybrid13<<<grid, dim3(256, 1, 1), 0, stream>>>(tin, wt3h, wmtA, bias, b_om, out);
    } else if (ws_size >= WS_MID) {
        unsigned short* wt3 = (unsigned short*)d_ws;
        float* wmt = (float*)((char*)d_ws + (size_t)WT3_ELEMS * 2);
        int total = WT3_ELEMS + WMT_ELEMS;
        prep_w<<<(total + 255) / 256, 256, 0, stream>>>(weight, w_om, wt3, wmt);
        dim3 grid(2, 128, 8);
        dcn_hybrid7<<<grid, dim3(256, 1, 1), 0, stream>>>(input, wt3, bias, wmt, b_om, out);
    } else {
        dim3 grid(2, 32, 8);
        dcn_fb<<<grid, dim3(64, 4, 1), 0, stream>>>(input, weight, bias, w_om, b_om, out);
    }
}

// Round 15
// 147.897 us; speedup vs baseline: 1.0359x; 1.0359x over previous
//
#include <hip/hip_runtime.h>
#include <math.h>

#define HW (128*128)

typedef short short8 __attribute__((ext_vector_type(8)));
typedef float floatx4 __attribute__((ext_vector_type(4)));
typedef unsigned int uintx4 __attribute__((ext_vector_type(4)));
typedef _Float16 half2v __attribute__((ext_vector_type(2)));
typedef _Float16 half8v __attribute__((ext_vector_type(8)));

#define MFMA(a,b,c)   __builtin_amdgcn_mfma_f32_16x16x32_bf16((a),(b),(c),0,0,0)
#define MFMA16(a,b,c) __builtin_amdgcn_mfma_f32_16x16x32_f16((a),(b),(c),0,0,0)

union V16 { uintx4 u; half2v h2[4]; half8v h8; _Float16 h[8]; };

// ---------------- workspace layout ----------------
#define WT3_ELEMS   (9*3*4*64*8)         // [kk][ks][quad][o][i], c=ks*32+quad*8+i
#define WMTA_ELEMS  (19*2*4*16*8)        // [kt][n][quad][m15][i]
#define WMT_ELEMS   (594*27)             // MID tier fp32
#define TIN_BYTES   ((size_t)8*HW*64*2)  // 16 MB
#define WT3_OFF     TIN_BYTES
#define WMTA_OFF    (WT3_OFF + (size_t)WT3_ELEMS*2)
#define WS_FULL     (WMTA_OFF + (size_t)WMTA_ELEMS*2)
#define WS_MID      ((size_t)WT3_ELEMS*2 + (size_t)WMT_ELEMS*4)

static __device__ __forceinline__ unsigned short f2bf(float x) {
    unsigned u = __float_as_uint(x);
    unsigned r = u + 0x7FFFu + ((u >> 16) & 1u);
    return (unsigned short)(r >> 16);
}

static __device__ __forceinline__ unsigned cvt_pk_bf16(float lo, float hi) {
    unsigned r;
    asm("v_cvt_pk_bf16_f32 %0, %1, %2" : "=v"(r) : "v"(lo), "v"(hi));
    return r;
}

// ---------------- prep: fp16 weights (FULL tier) ----------------
__global__ __launch_bounds__(256) void prep_w16(
    const float* __restrict__ weight, const float* __restrict__ w_om,
    _Float16* __restrict__ wt3, _Float16* __restrict__ wmtA)
{
    int t = blockIdx.x * 256 + threadIdx.x;
    if (t < WT3_ELEMS) {
        int i = t & 7;  int u = t >> 3;
        int o = u & 63; u >>= 6;
        int quad = u & 3; u >>= 2;
        int ks = u % 3, kk = u / 3;
        int c = ks * 32 + quad * 8 + i;
        float v = (c < 66) ? weight[o * 594 + c * 9 + kk] : 0.0f;
        wt3[t] = (_Float16)v;
    } else if (t < WT3_ELEMS + WMTA_ELEMS) {
        int t2 = t - WT3_ELEMS;
        int i = t2 & 7;  int u = t2 >> 3;
        int m15 = u & 15; u >>= 4;
        int quad = u & 3; u >>= 2;
        int n = u & 1;    int kt = u >> 1;
        int o = 16 * n + m15;
        float v = 0.0f;
        if (o < 27) {
            if (kt < 18) {
                int j = kt >> 1, c = (kt & 1) * 32 + quad * 8 + i;
                v = w_om[o * 594 + c * 9 + j];
            } else {
                int q = quad * 8 + i;
                if (q < 18) {
                    int j = q >> 1, c = 64 + (q & 1);
                    v = w_om[o * 594 + c * 9 + j];
                }
            }
        }
        wmtA[t2] = (_Float16)v;
    }
}

// ---------------- prep: NCHW fp32 -> NHWC fp16 transpose (vectorized) -------
__global__ __launch_bounds__(256) void prep_t(
    const float* __restrict__ in, _Float16* __restrict__ t_out)
{
    __shared__ float s[64][129];
    const int y = blockIdx.x, b = blockIdx.y;
    const int tid = threadIdx.x, lane = tid & 63, w = tid >> 6;
    const float* src = in + (size_t)b * 64 * HW + y * 128;
#pragma unroll
    for (int i = 0; i < 16; ++i) {
        int c = w * 16 + i;
        s[c][lane]      = src[(size_t)c * HW + lane];
        s[c][lane + 64] = src[(size_t)c * HW + lane + 64];
    }
    __syncthreads();
    _Float16* dst = t_out + ((size_t)b * HW + (size_t)y * 128) * 64;
#pragma unroll
    for (int it = 0; it < 4; ++it) {
        int idx = it * 256 + tid;        // 0..1023
        int x = idx >> 3, g = idx & 7;   // pixel x, channel-group g
        V16 v;
#pragma unroll
        for (int j = 0; j < 8; ++j)
            v.h[j] = (_Float16)s[g * 8 + j][x];
        *(uintx4*)&dst[(size_t)x * 64 + g * 8] = v.u;
    }
}

// ---------------- prep: weights (bf16+fp32, MID tier) ----------------
__global__ __launch_bounds__(256) void prep_w(
    const float* __restrict__ weight, const float* __restrict__ w_om,
    unsigned short* __restrict__ wt3, float* __restrict__ wmt)
{
    int t = blockIdx.x * 256 + threadIdx.x;
    if (t < WT3_ELEMS) {
        int i = t & 7;  int u = t >> 3;
        int o = u & 63; u >>= 6;
        int quad = u & 3; u >>= 2;
        int ks = u % 3, kk = u / 3;
        int c = ks * 32 + quad * 8 + i;
        float v = (c < 66) ? weight[o * 594 + c * 9 + kk] : 0.0f;
        wt3[t] = f2bf(v);
    } else if (t < WT3_ELEMS + WMT_ELEMS) {
        int t2 = t - WT3_ELEMS;
        int oc = t2 % 27, ck = t2 / 27;
        wmt[t2] = w_om[oc * 594 + ck];
    }
}

// Round 2:  XCD-pinning remap (FETCH 268->18.5MB, verified).
// Round 6:  NHWC fp16 shadow input (274 -> 214us).
// Round 7:  Phase A on matrix cores (214 -> 171us).
// Round 10: spill fix (171 -> 119.6us).
// Round 13: LDS gather tile (119.6 -> 69.2us).
// Round 14: LDS diet to 54272B: 3rd block did NOT fit (occupancy flat at
//   19.7% despite 3x54272 <= 163840) -> per-CU usable LDS < 160KiB pool.
// Round 15: (a) LDS OVERLAY: s_off/mask fp16 arrays (3456B) aliased INSIDE
//   the s_om buffer (7020B) - disjoint lifetimes, ordering enforced by
//   read-om-to-regs + barrier before the aliased write. Total 50540B ->
//   50688 granulated; 3x = 152064, ~11.8KB headroom vs any reserve.
//   Tell-tale: Occupancy 19.7 -> ~29 (3 blocks/CU). If still flat, usable
//   LDS <= 128KB and the occupancy path is closed.
//   (b) paired tile reads: chunk q+4 sits at ushort-index idx(q)^32 (no
//   carries since q<4) -> 8 reads need 4 addr computations + 4 XORs.
__global__ __launch_bounds__(256, 2) void dcn_hybrid14(
    const _Float16* __restrict__ t_in,
    const _Float16* __restrict__ wt3h,
    const _Float16* __restrict__ wmtA,
    const float* __restrict__ bias,
    const float* __restrict__ b_om,
    float* __restrict__ out)
{
    // tile line (r,c) = image (clamp(ho-2+r), clamp(wo0-2+c)), 64ch fp16 =
    // 128B = 8 chunks of 16B; chunk k stored at slot k ^ (c&7).
    __shared__ __align__(16) unsigned short s_tile[5 * 68 * 64];   // 43520 B
    // multi-use buffer: [Phase A] om fp32 27x65 | [Phase B] off/mask fp16
    // (first 3456 B) | [final epilogue] 16x65 fp32 redistribution.
    __shared__ __align__(16) float s_buf[27 * 65];                 // 7020 B

    _Float16* s_offh16 = (_Float16*)s_buf;          // [0,   1152) B
    _Float16* s_offw16 = (_Float16*)s_buf + 576;    // [1152,2304) B
    _Float16* s_mask16 = (_Float16*)s_buf + 1152;   // [2304,3456) B

    const int tid  = threadIdx.x;
    const int lane = tid & 63;
    const int w    = tid >> 6;
    const int wu   = __builtin_amdgcn_readfirstlane(w);
    const int m15  = lane & 15;
    const int quad = lane >> 4;

    // ---- XCD-pinning remap
    const int L   = blockIdx.x + 2 * (blockIdx.y + 128 * blockIdx.z);
    const int b   = L & 7;
    const int r   = L >> 3;
    const int ho  = r >> 1;
    const int wo0 = (r & 1) * 64;

    const float invH = 1.0f / 128.0f;

    const int pixL = wu * 16 + m15;
    const int wob  = wo0 + pixL;

    const _Float16* tinb = t_in + (size_t)b * HW * 64;
    const _Float16* tinq = tinb + quad * 8;     // global-fallback base

    // ---------------- stage the tile (coalesced, once) ----------------
    for (int Lt = tid; Lt < 340; Lt += 256) {
        int rt = Lt / 68, ct = Lt - rt * 68;
        int gy = min(max(ho - 2 + rt, 0), 127);
        int gx = min(max(wo0 - 2 + ct, 0), 127);
        const uintx4* src = (const uintx4*)(tinb + ((size_t)gy * 128 + gx) * 64);
        uintx4* dst = (uintx4*)&s_tile[(size_t)Lt * 64];
        int sw = ct & 7;
#pragma unroll
        for (int k = 0; k < 8; ++k)
            dst[k ^ sw] = src[k];
    }

    // ushort index of logical 16B chunk q of tile line (rt,ct); q+4 = idx^32
    auto tidx = [&](int rt, int ct, int q) -> int {
        return (((rt * 68 + ct) << 3) + (q ^ (ct & 7))) << 3;
    };
    auto tld = [&](int i) -> uintx4 {
        return *(const uintx4*)&s_tile[i];
    };

    // ---- 9 fixed-tap tile coords / validity for pixel (ho, wob)
    int   tr9[9], tc9[9];
    float ok9[9];
#pragma unroll
    for (int j = 0; j < 9; ++j) {
        int y = ho - 1 + j / 3;
        int x = wob - 1 + j % 3;
        bool ok = ((unsigned)y < 128u) && ((unsigned)x < 128u);
        int yc = min(max(y, 0), 127), xc = min(max(x, 0), 127);
        tr9[j] = yc - (ho - 2);          // in [0,5)
        tc9[j] = xc - (wo0 - 2);         // in [0,68)
        ok9[j] = ok ? 1.0f : 0.0f;
    }
    __syncthreads();   // tile staged

    // ---------------- Phase A: offset conv via f16 MFMA (tile reads) ------
    floatx4 a0 = (floatx4){0.f, 0.f, 0.f, 0.f};
    floatx4 a1 = (floatx4){0.f, 0.f, 0.f, 0.f};

#pragma unroll
    for (int j = 0; j < 9; ++j) {
        _Float16 okh = (_Float16)ok9[j];
        half2v okh2 = {okh, okh};
        int i0 = tidx(tr9[j], tc9[j], quad);
        V16 bbA, bbB;
        bbA.u = tld(i0);
        bbB.u = tld(i0 ^ 32);
#pragma unroll
        for (int rr = 0; rr < 4; ++rr) {
            bbA.h2[rr] = bbA.h2[rr] * okh2;
            bbB.h2[rr] = bbB.h2[rr] * okh2;
        }
#pragma unroll
        for (int h = 0; h < 2; ++h) {
            const int kt = j * 2 + h;
            const _Float16* ap = wmtA + (size_t)((kt * 2) * 4 + quad) * 128 + m15 * 8;
            half8v A0 = *(const half8v*)ap;
            half8v A1 = *(const half8v*)(ap + 512);
            a0 = MFMA16(A0, h ? bbB.h8 : bbA.h8, a0);
            a1 = MFMA16(A1, h ? bbB.h8 : bbA.h8, a1);
        }
    }
    {   // coord K-tile (kt=18)
        V16 bb;
#pragma unroll
        for (int rr = 0; rr < 4; ++rr) {
            float ve = 0.f, vo = 0.f;
            int j = quad * 4 + rr;
            if (j < 9) {
                int y = ho - 1 + j / 3;
                int x = wob - 1 + j % 3;
                bool ok = ((unsigned)y < 128u) && ((unsigned)x < 128u);
                ve = ok ? y * invH : 0.f;
                vo = ok ? (x * invH - 0.5f) : 0.f;
            }
            bb.h2[rr] = (half2v){(_Float16)ve, (_Float16)vo};
        }
        const _Float16* ap = wmtA + (size_t)((18 * 2) * 4 + quad) * 128 + m15 * 8;
        half8v A0 = *(const half8v*)ap;
        half8v A1 = *(const half8v*)(ap + 512);
        a0 = MFMA16(A0, bb.h8, a0);
        a1 = MFMA16(A1, bb.h8, a1);
    }

    // stage om to LDS: s_buf[oc][pix] fp32, 27 rows (rows >= 27 don't exist)
#pragma unroll
    for (int rr = 0; rr < 4; ++rr) {
        s_buf[(quad * 4 + rr) * 65 + pixL] = a0[rr];
        if (quad * 4 + rr < 11)
            s_buf[(16 + quad * 4 + rr) * 65 + pixL] = a1[rr];
    }
    __syncthreads();

    // ---- idx/mask epilogue: READ om to regs, barrier, THEN write aliased
    // fp16 offs/mask into the same buffer + fp32 nt stores.
    {
        float* out_idx = out + (size_t)8 * 64 * HW;
        float* out_msk = out_idx + (size_t)8 * 18 * HW;
        const int wo = wo0 + lane;
        const int p  = ho * 128 + wo;
        const float hg = ho * invH;
        const float wg = wo * invH - 0.5f;
        int oc0 = wu * 7;
        int noc = (wu == 3) ? 6 : 7;
        float sv[7];
        for (int t = 0; t < noc; ++t)
            sv[t] = s_buf[(oc0 + t) * 65 + lane];
        __syncthreads();                 // all om reads done before alias write
        for (int t = 0; t < noc; ++t) {
            int oc = oc0 + t;
            float s = b_om[oc] + sv[t];
            if (oc < 9) {
                __builtin_nontemporal_store(hg + (float)(oc / 3 - 1) + s,
                    &out_idx[((size_t)b * 18 + oc) * HW + p]);
                if (oc & 1) s_offw16[(oc >> 1) * 64 + lane] = (_Float16)s;
                else        s_offh16[(oc >> 1) * 64 + lane] = (_Float16)s;
            } else if (oc < 18) {
                __builtin_nontemporal_store(wg + (float)((oc - 9) % 3 - 1) + s,
                    &out_idx[((size_t)b * 18 + oc) * HW + p]);
                if (oc & 1) s_offw16[(oc >> 1) * 64 + lane] = (_Float16)s;
                else        s_offh16[(oc >> 1) * 64 + lane] = (_Float16)s;
            } else {
                float mkv = 1.0f / (1.0f + __expf(-s));
                __builtin_nontemporal_store(mkv,
                    &out_msk[((size_t)b * 9 + (oc - 18)) * HW + p]);
                s_mask16[(oc - 18) * 64 + lane] = (_Float16)mkv;
            }
        }
    }
    __syncthreads();   // offs/mask ready

    // ---------------- Phase B: tile ds_reads + f16 MFMA -------------------
    floatx4 acc[4];
#pragma unroll
    for (int t = 0; t < 4; ++t) acc[t] = (floatx4){0.f, 0.f, 0.f, 0.f};

    const int hom1 = ho - 1;

#pragma unroll
    for (int kk = 0; kk < 9; ++kk) {
        float offh = (float)s_offh16[kk * 64 + pixL];
        float offw = (float)s_offw16[kk * 64 + pixL];
        float mval = (float)s_mask16[kk * 64 + pixL];

        float ph = offh + (float)(kk / 3) + (float)hom1;
        float pw = offw + (float)(kk % 3) + (float)(wob - 1);
        float h0f = floorf(ph), w0f = floorf(pw);
        int h0 = (int)h0f, w0 = (int)w0f;
        int h1 = h0 + 1, w1 = w0 + 1;
        float lh = ph - h0f, lw = pw - w0f;
        float hh = 1.0f - lh, hwp = 1.0f - lw;
        bool okh0 = (unsigned)h0 < 128u, okh1 = (unsigned)h1 < 128u;
        bool okw0 = (unsigned)w0 < 128u, okw1 = (unsigned)w1 < 128u;
        float w00 = (okh0 && okw0) ? hh * hwp * mval : 0.0f;
        float w01 = (okh0 && okw1) ? hh * lw  * mval : 0.0f;
        float w10 = (okh1 && okw0) ? lh * hwp * mval : 0.0f;
        float w11 = (okh1 && okw1) ? lh * lw  * mval : 0.0f;
        int h0c = min(max(h0, 0), 127), h1c = min(max(h1, 0), 127);
        int w0c = min(max(w0, 0), 127), w1c = min(max(w1, 0), 127);

        int r0 = h0c - (ho - 2), r1 = h1c - (ho - 2);
        int c0 = w0c - (wo0 - 2), c1 = w1c - (wo0 - 2);
        bool intile = ((unsigned)r0 < 5u) && ((unsigned)r1 < 5u)
                   && ((unsigned)c0 < 68u) && ((unsigned)c1 < 68u);

        V16 A00, A01, A10, A11, B00, B01, B10, B11;
        if (__all(intile)) {
            int i00 = tidx(r0, c0, quad), i01 = tidx(r0, c1, quad);
            int i10 = tidx(r1, c0, quad), i11 = tidx(r1, c1, quad);
            A00.u = tld(i00);      A01.u = tld(i01);
            A10.u = tld(i10);      A11.u = tld(i11);
            B00.u = tld(i00 ^ 32); B01.u = tld(i01 ^ 32);
            B10.u = tld(i10 ^ 32); B11.u = tld(i11 ^ 32);
        } else {
            int o00 = h0c * 128 + w0c, o01 = h0c * 128 + w1c;
            int o10 = h1c * 128 + w0c, o11 = h1c * 128 + w1c;
            A00.u = *(const uintx4*)(tinq + (size_t)o00 * 64);
            A01.u = *(const uintx4*)(tinq + (size_t)o01 * 64);
            A10.u = *(const uintx4*)(tinq + (size_t)o10 * 64);
            A11.u = *(const uintx4*)(tinq + (size_t)o11 * 64);
            B00.u = *(const uintx4*)(tinq + (size_t)o00 * 64 + 32);
            B01.u = *(const uintx4*)(tinq + (size_t)o01 * 64 + 32);
            B10.u = *(const uintx4*)(tinq + (size_t)o10 * 64 + 32);
            B11.u = *(const uintx4*)(tinq + (size_t)o11 * 64 + 32);
        }

        _Float16 h00 = (_Float16)w00, h01 = (_Float16)w01;
        _Float16 h10 = (_Float16)w10, h11 = (_Float16)w11;
        half2v W00 = {h00, h00}, W01 = {h01, h01};
        half2v W10 = {h10, h10}, W11 = {h11, h11};

        V16 b0, b1, b2;
#pragma unroll
        for (int rr = 0; rr < 4; ++rr) {
            b0.h2[rr] = A00.h2[rr] * W00 + A01.h2[rr] * W01
                      + A10.h2[rr] * W10 + A11.h2[rr] * W11;
            b1.h2[rr] = B00.h2[rr] * W00 + B01.h2[rr] * W01
                      + B10.h2[rr] * W10 + B11.h2[rr] * W11;
        }
        float c64 = (w00 + w01) * (h0c * invH) + (w10 + w11) * (h1c * invH);
        float c65 = (w00 + w10) * (w0c * invH - 0.5f) + (w01 + w11) * (w1c * invH - 0.5f);
        b2.u = (uintx4){0u, 0u, 0u, 0u};
        if (quad == 0) b2.h2[0] = (half2v){(_Float16)c64, (_Float16)c65};

        const _Float16* w0p = wt3h + (size_t)(kk * 3) * 2048 + quad * 512;
        const _Float16* w1p = w0p + 2048;
        const _Float16* w2p = w0p + 4096;
#pragma unroll
        for (int t = 0; t < 4; ++t) {
            int o8 = (16 * t + m15) * 8;
            half8v A0 = *(const half8v*)&w0p[o8];
            half8v A1 = *(const half8v*)&w1p[o8];
            half8v A2 = *(const half8v*)&w2p[o8];
            acc[t] = MFMA16(A0, b0.h8, acc[t]);
            acc[t] = MFMA16(A1, b1.h8, acc[t]);
            acc[t] = MFMA16(A2, b2.h8, acc[t]);
        }
    }

    // ---------- epilogue: LDS redistribute (4 x 16 ch) -> full-line nt stores
    // acc[t][rr] holds o = 16t + quad*4 + rr for pixel pixL (verified R7).
    // s_buf's offs data is dead now; reuse rows 0..15.
    {
        const size_t rowbase = (size_t)b * 64 * HW + (size_t)ho * 128 + wo0;
#pragma unroll
        for (int t = 0; t < 4; ++t) {
            __syncthreads();   // prev round's reads (or Phase B) done
#pragma unroll
            for (int rr = 0; rr < 4; ++rr)
                s_buf[(quad * 4 + rr) * 65 + pixL] = acc[t][rr];
            __syncthreads();
#pragma unroll
            for (int k = 0; k < 4; ++k) {
                int o = 16 * t + wu * 4 + k;
                float v = s_buf[(wu * 4 + k) * 65 + lane] + bias[o];
                __builtin_nontemporal_store(v, &out[(size_t)o * HW + rowbase + lane]);
            }
        }
    }
}

// ---------------- MID tier: R5 kernel (verified), bf16 MFMA ----------------
__global__ __launch_bounds__(256, 4) void dcn_hybrid7(
    const float* __restrict__ input,
    const unsigned short* __restrict__ wt3,
    const float* __restrict__ bias,
    const float* __restrict__ wmt,
    const float* __restrict__ b_om,
    float* __restrict__ out)
{
    __shared__ float s_red[4 * 27 * 64];
    __shared__ float s_offh[9 * 64], s_offw[9 * 64], s_maskf[9 * 64];

    const int tid  = threadIdx.x;
    const int lane = tid & 63;
    const int w    = tid >> 6;
    const int wu   = __builtin_amdgcn_readfirstlane(w);
    const int m15  = lane & 15;
    const int quad = lane >> 4;

    const int L   = blockIdx.x + 2 * (blockIdx.y + 128 * blockIdx.z);
    const int b   = L & 7;
    const int r   = L >> 3;
    const int ho  = r >> 1;
    const int wo0 = (r & 1) * 64;

    const int wo  = wo0 + lane;
    const int p   = ho * 128 + wo;
    const float invH = 1.0f / 128.0f;

    const float* inb = input + (size_t)b * 64 * HW;

    int   a9[9];
    float okf[9], vy[9], vx[9];
#pragma unroll
    for (int j = 0; j < 9; ++j) {
        int y = ho - 1 + j / 3;
        int x = wo - 1 + j % 3;
        bool ok = ((unsigned)y < 128u) && ((unsigned)x < 128u);
        int yc = min(max(y, 0), 127), xc = min(max(x, 0), 127);
        a9[j]  = yc * 128 + xc;
        okf[j] = ok ? 1.0f : 0.0f;
        vy[j]  = ok ? y * invH : 0.0f;
        vx[j]  = ok ? (x * invH - 0.5f) : 0.0f;
    }

    const int nc = (wu < 2) ? 17 : 16;

    float om_part[27];
#pragma unroll
    for (int oc = 0; oc < 27; ++oc) om_part[oc] = 0.0f;

    {
        float va[9], vb[9];
        {
            const float* pc = inb + wu * HW;
#pragma unroll
            for (int j = 0; j < 9; ++j) va[j] = pc[a9[j]] * okf[j];
        }
        for (int i = 0; i < nc; ++i) {
            int c = wu + 4 * i;
            if (i + 1 < nc) {
                int cn = c + 4;
                if (cn < 64) {
                    const float* pc = inb + cn * HW;
#pragma unroll
                    for (int j = 0; j < 9; ++j) vb[j] = pc[a9[j]] * okf[j];
                } else if (cn == 64) {
#pragma unroll
                    for (int j = 0; j < 9; ++j) vb[j] = vy[j];
                } else {
#pragma unroll
                    for (int j = 0; j < 9; ++j) vb[j] = vx[j];
                }
            }
#pragma unroll
            for (int j = 0; j < 9; ++j) {
                const float* wp = wmt + (c * 9 + j) * 27;
#pragma unroll
                for (int oc = 0; oc < 27; ++oc)
                    om_part[oc] = fmaf(va[j], wp[oc], om_part[oc]);
            }
#pragma unroll
            for (int j = 0; j < 9; ++j) va[j] = vb[j];
        }
    }
#pragma unroll
    for (int oc = 0; oc < 27; ++oc)
        s_red[(w * 27 + oc) * 64 + lane] = om_part[oc];
    __syncthreads();

    {
        float* out_idx = out + (size_t)8 * 64 * HW;
        float* out_msk = out_idx + (size_t)8 * 18 * HW;
        const float hg = ho * invH;
        const float wg = wo * invH - 0.5f;
        int oc0 = wu * 7;
        int noc = (wu == 3) ? 6 : 7;
        for (int t = 0; t < noc; ++t) {
            int oc = oc0 + t;
            float s = b_om[oc]
                    + s_red[(0 * 27 + oc) * 64 + lane]
                    + s_red[(1 * 27 + oc) * 64 + lane]
                    + s_red[(2 * 27 + oc) * 64 + lane]
                    + s_red[(3 * 27 + oc) * 64 + lane];
            if (oc < 9) {
                out_idx[((size_t)b * 18 + oc) * HW + p] = hg + (float)(oc / 3 - 1) + s;
                if (oc & 1) s_offw[(oc >> 1) * 64 + lane] = s;
                else        s_offh[(oc >> 1) * 64 + lane] = s;
            } else if (oc < 18) {
                out_idx[((size_t)b * 18 + oc) * HW + p] = wg + (float)((oc - 9) % 3 - 1) + s;
                if (oc & 1) s_offw[(oc >> 1) * 64 + lane] = s;
                else        s_offh[(oc >> 1) * 64 + lane] = s;
            } else {
                float mkv = 1.0f / (1.0f + __expf(-s));
                out_msk[((size_t)b * 9 + (oc - 18)) * HW + p] = mkv;
                s_maskf[(oc - 18) * 64 + lane] = mkv;
            }
        }
    }
    __syncthreads();

    const int pixL = wu * 16 + m15;
    const int wob  = wo0 + pixL;
    const int hom1 = ho - 1;

    floatx4 acc[4];
#pragma unroll
    for (int t = 0; t < 4; ++t) acc[t] = (floatx4){0.f, 0.f, 0.f, 0.f};

    const float* base0 = inb + (size_t)(quad * 8) * HW;
    const float* base1 = base0 + (size_t)32 * HW;

#pragma unroll
    for (int kk = 0; kk < 9; ++kk) {
        float offh = s_offh[kk * 64 + pixL];
        float offw = s_offw[kk * 64 + pixL];
        float mval = s_maskf[kk * 64 + pixL];

        float ph = offh + (float)(kk / 3) + (float)hom1;
        float pw = offw + (float)(kk % 3) + (float)(wob - 1);
        float h0f = floorf(ph), w0f = floorf(pw);
        int h0 = (int)h0f, w0 = (int)w0f;
        int h1 = h0 + 1, w1 = w0 + 1;
        float lh = ph - h0f, lw = pw - w0f;
        float hh = 1.0f - lh, hwp = 1.0f - lw;
        bool okh0 = (unsigned)h0 < 128u, okh1 = (unsigned)h1 < 128u;
        bool okw0 = (unsigned)w0 < 128u, okw1 = (unsigned)w1 < 128u;
        float w00 = (okh0 && okw0) ? hh * hwp * mval : 0.0f;
        float w01 = (okh0 && okw1) ? hh * lw  * mval : 0.0f;
        float w10 = (okh1 && okw0) ? lh * hwp * mval : 0.0f;
        float w11 = (okh1 && okw1) ? lh * lw  * mval : 0.0f;
        int h0c = min(max(h0, 0), 127), h1c = min(max(h1, 0), 127);
        int w0c = min(max(w0, 0), 127), w1c = min(max(w1, 0), 127);
        int o00 = h0c * 128 + w0c, o01 = h0c * 128 + w1c;
        int o10 = h1c * 128 + w0c, o11 = h1c * 128 + w1c;

        unsigned pk0[4], pk1[4];
#pragma unroll
        for (int j = 0; j < 4; ++j) {
            const float* pa = base0 + (size_t)(2 * j) * HW;
            const float* pb = pa + HW;
            float ca = w00 * pa[o00] + w01 * pa[o01] + w10 * pa[o10] + w11 * pa[o11];
            float cb = w00 * pb[o00] + w01 * pb[o01] + w10 * pb[o10] + w11 * pb[o11];
            pk0[j] = cvt_pk_bf16(ca, cb);
            const float* pa1 = base1 + (size_t)(2 * j) * HW;
            const float* pb1 = pa1 + HW;
            float ca1 = w00 * pa1[o00] + w01 * pa1[o01] + w10 * pa1[o10] + w11 * pa1[o11];
            float cb1 = w00 * pb1[o00] + w01 * pb1[o01] + w10 * pb1[o10] + w11 * pb1[o11];
            pk1[j] = cvt_pk_bf16(ca1, cb1);
        }
        union { uintx4 u; short8 s; } b0, b1, b2;
        b0.u = (uintx4){pk0[0], pk0[1], pk0[2], pk0[3]};
        b1.u = (uintx4){pk1[0], pk1[1], pk1[2], pk1[3]};
        float c64 = (w00 + w01) * (h0c * invH) + (w10 + w11) * (h1c * invH);
        float c65 = (w00 + w10) * (w0c * invH - 0.5f) + (w01 + w11) * (w1c * invH - 0.5f);
        unsigned pk2 = (quad == 0) ? cvt_pk_bf16(c64, c65) : 0u;
        b2.u = (uintx4){pk2, 0u, 0u, 0u};

        const unsigned short* w0p = wt3 + (size_t)(kk * 3 + 0) * 2048 + quad * 512;
        const unsigned short* w1p = w0p + 2048;
        const unsigned short* w2p = w0p + 4096;
#pragma unroll
        for (int t = 0; t < 4; ++t) {
            int o8 = (16 * t + m15) * 8;
            short8 A0 = *(const short8*)&w0p[o8];
            short8 A1 = *(const short8*)&w1p[o8];
            short8 A2 = *(const short8*)&w2p[o8];
            acc[t] = MFMA(A0, b0.s, acc[t]);
            acc[t] = MFMA(A1, b1.s, acc[t]);
            acc[t] = MFMA(A2, b2.s, acc[t]);
        }
    }

    {
        size_t pb = (size_t)ho * 128 + wob;
#pragma unroll
        for (int t = 0; t < 4; ++t) {
#pragma unroll
            for (int rr = 0; rr < 4; ++rr) {
                int o = 16 * t + quad * 4 + rr;
                out[((size_t)b * 64 + o) * HW + pb] = acc[t][rr] + bias[o];
            }
        }
    }
}

// ------------------- fallback (no workspace): fp32 baseline -------------------
__global__ __launch_bounds__(256) void dcn_fb(
    const float* __restrict__ input,
    const float* __restrict__ wmain,
    const float* __restrict__ bias,
    const float* __restrict__ wom,
    const float* __restrict__ b_om,
    float* __restrict__ out)
{
    const int wo = blockIdx.x * 64 + threadIdx.x;
    const int ho = blockIdx.y * 4 + threadIdx.y;
    const int b  = blockIdx.z;
    const int p  = ho * 128 + wo;
    const float invH = 1.0f / 128.0f;
    const float* inb = input + (size_t)b * 64 * HW;

    float om[27];
#pragma unroll
    for (int oc = 0; oc < 27; ++oc) om[oc] = b_om[oc];

    for (int c = 0; c < 64; ++c) {
        const float* pc = inb + c * HW;
        float v[9];
#pragma unroll
        for (int kh = 0; kh < 3; ++kh) {
            int y = ho - 1 + kh;
            bool oky = (unsigned)y < 128u;
#pragma unroll
            for (int kw = 0; kw < 3; ++kw) {
                int x = wo - 1 + kw;
                bool ok = oky && ((unsigned)x < 128u);
                v[kh*3+kw] = ok ? pc[y * 128 + x] : 0.0f;
            }
        }
#pragma unroll
        for (int oc = 0; oc < 27; ++oc)
#pragma unroll
            for (int i = 0; i < 9; ++i)
                om[oc] = fmaf(v[i], wom[oc*594 + c*9 + i], om[oc]);
    }
    {
        float v64[9], v65[9];
#pragma unroll
        for (int kh = 0; kh < 3; ++kh) {
            int y = ho - 1 + kh;
            bool oky = (unsigned)y < 128u;
#pragma unroll
            for (int kw = 0; kw < 3; ++kw) {
                int x = wo - 1 + kw;
                bool ok = oky && ((unsigned)x < 128u);
                v64[kh*3+kw] = ok ? y * invH : 0.0f;
                v65[kh*3+kw] = ok ? (x * invH - 0.5f) : 0.0f;
            }
        }
#pragma unroll
        for (int oc = 0; oc < 27; ++oc)
#pragma unroll
            for (int i = 0; i < 9; ++i) {
                om[oc] = fmaf(v64[i], wom[oc*594 + 64*9 + i], om[oc]);
                om[oc] = fmaf(v65[i], wom[oc*594 + 65*9 + i], om[oc]);
            }
    }

    const float hg = ho * invH;
    const float wg = wo * invH - 0.5f;
    float* out_idx = out + (size_t)8 * 64 * HW;
    float* out_msk = out_idx + (size_t)8 * 18 * HW;
#pragma unroll
    for (int cc = 0; cc < 9; ++cc)
        out_idx[((size_t)b*18 + cc)*HW + p] = hg + (float)(cc/3 - 1) + om[cc];
#pragma unroll
    for (int cc = 9; cc < 18; ++cc)
        out_idx[((size_t)b*18 + cc)*HW + p] = wg + (float)((cc-9)%3 - 1) + om[cc];

    float mk[9];
#pragma unroll
    for (int kk = 0; kk < 9; ++kk) {
        mk[kk] = 1.0f / (1.0f + __expf(-om[18+kk]));
        out_msk[((size_t)b*9 + kk)*HW + p] = mk[kk];
    }

    float acc[64];
#pragma unroll
    for (int o = 0; o < 64; ++o) acc[o] = bias[o];

#pragma unroll
    for (int kk = 0; kk < 9; ++kk) {
        float ph = om[2*kk]   + (float)(kk/3) + (float)(ho - 1);
        float pw = om[2*kk+1] + (float)(kk%3) + (float)(wo - 1);
        float h0f = floorf(ph), w0f = floorf(pw);
        int h0 = (int)h0f, w0 = (int)w0f;
        int h1 = h0 + 1, w1 = w0 + 1;
        float lh = ph - h0f, lw = pw - w0f;
        float hh = 1.0f - lh, hwp = 1.0f - lw;
        float m = mk[kk];
        bool okh0 = (unsigned)h0 < 128u, okh1 = (unsigned)h1 < 128u;
        bool okw0 = (unsigned)w0 < 128u, okw1 = (unsigned)w1 < 128u;
        float w00 = (okh0 && okw0) ? hh*hwp*m : 0.0f;
        float w01 = (okh0 && okw1) ? hh*lw*m  : 0.0f;
        float w10 = (okh1 && okw0) ? lh*hwp*m : 0.0f;
        float w11 = (okh1 && okw1) ? lh*lw*m  : 0.0f;
        int h0c = min(max(h0, 0), 127), h1c = min(max(h1, 0), 127);
        int w0c = min(max(w0, 0), 127), w1c = min(max(w1, 0), 127);
        int o00 = h0c*128 + w0c, o01 = h0c*128 + w1c;
        int o10 = h1c*128 + w0c, o11 = h1c*128 + w1c;

        for (int c = 0; c < 64; ++c) {
            const float* pc = inb + c * HW;
            float col = w00*pc[o00] + w01*pc[o01] + w10*pc[o10] + w11*pc[o11];
#pragma unroll
            for (int o = 0; o < 64; ++o)
                acc[o] = fmaf(col, wmain[o*594 + c*9 + kk], acc[o]);
        }
        {
            float y0 = h0c * invH, y1 = h1c * invH;
            float x0 = w0c * invH - 0.5f, x1 = w1c * invH - 0.5f;
            float col64 = (w00 + w01)*y0 + (w10 + w11)*y1;
            float col65 = (w00 + w10)*x0 + (w01 + w11)*x1;
#pragma unroll
            for (int o = 0; o < 64; ++o) {
                acc[o] = fmaf(col64, wmain[o*594 + 64*9 + kk], acc[o]);
                acc[o] = fmaf(col65, wmain[o*594 + 65*9 + kk], acc[o]);
            }
        }
    }

#pragma unroll
    for (int o = 0; o < 64; ++o)
        out[((size_t)b*64 + o)*HW + p] = acc[o];
}

extern "C" void kernel_launch(void* const* d_in, const int* in_sizes, int n_in,
                              void* d_out, int out_size, void* d_ws, size_t ws_size,
                              hipStream_t stream)
{
    const float* input  = (const float*)d_in[0];
    const float* weight = (const float*)d_in[1];
    const float* bias   = (const float*)d_in[2];
    const float* w_om   = (const float*)d_in[3];
    const float* b_om   = (const float*)d_in[4];
    float* out = (float*)d_out;

    if (ws_size >= WS_FULL) {
        _Float16* tin  = (_Float16*)d_ws;
        _Float16* wt3h = (_Float16*)((char*)d_ws + WT3_OFF);
        _Float16* wmtA = (_Float16*)((char*)d_ws + WMTA_OFF);
        int total = WT3_ELEMS + WMTA_ELEMS;
        prep_w16<<<(total + 255) / 256, 256, 0, stream>>>(weight, w_om, wt3h, wmtA);
        prep_t<<<dim3(128, 8), 256, 0, stream>>>(input, tin);
        dim3 grid(2, 128, 8);
        dcn_hybrid14<<<grid, dim3(256, 1, 1), 0, stream>>>(tin, wt3h, wmtA, bias, b_om, out);
    } else if (ws_size >= WS_MID) {
        unsigned short* wt3 = (unsigned short*)d_ws;
        float* wmt = (float*)((char*)d_ws + (size_t)WT3_ELEMS * 2);
        int total = WT3_ELEMS + WMT_ELEMS;
        prep_w<<<(total + 255) / 256, 256, 0, stream>>>(weight, w_om, wt3, wmt);
        dim3 grid(2, 128, 8);
        dcn_hybrid7<<<grid, dim3(256, 1, 1), 0, stream>>>(input, wt3, bias, wmt, b_om, out);
    } else {
        dim3 grid(2, 32, 8);
        dcn_fb<<<grid, dim3(64, 4, 1), 0, stream>>>(input, weight, bias, w_om, b_om, out);
    }
}

// Round 16
// 147.819 us; speedup vs baseline: 1.0364x; 1.0005x over previous
//
#include <hip/hip_runtime.h>
#include <math.h>

#define HW (128*128)

typedef short short8 __attribute__((ext_vector_type(8)));
typedef float floatx4 __attribute__((ext_vector_type(4)));
typedef unsigned int uintx4 __attribute__((ext_vector_type(4)));
typedef _Float16 half2v __attribute__((ext_vector_type(2)));
typedef _Float16 half8v __attribute__((ext_vector_type(8)));

#define MFMA16(a,b,c) __builtin_amdgcn_mfma_f32_16x16x32_f16((a),(b),(c),0,0,0)
#define MFMA(a,b,c)   __builtin_amdgcn_mfma_f32_16x16x32_bf16((a),(b),(c),0,0,0)

union V16 { uintx4 u; half2v h2[4]; half8v h8; _Float16 h[8]; };
union H2U { unsigned u; half2v h2; _Float16 h[2]; unsigned short us[2]; };

// ---------------- workspace layout ----------------
#define WT3_ELEMS   (9*3*4*64*8)         // [kk][ks][quad][o][i], c=ks*32+quad*8+i
#define WMTA_ELEMS  (19*2*4*16*8)        // [kt][n][quad][m15][i]
#define WMT_ELEMS   (594*27)             // MID tier fp32
#define TIN_BYTES   ((size_t)8*HW*64*2)  // 16 MB
#define WT3_OFF     TIN_BYTES
#define WMTA_OFF    (WT3_OFF + (size_t)WT3_ELEMS*2)
#define WS_FULL     (WMTA_OFF + (size_t)WMTA_ELEMS*2)
#define WS_MID      ((size_t)WT3_ELEMS*2 + (size_t)WMT_ELEMS*4)

static __device__ __forceinline__ unsigned short f2bf(float x) {
    unsigned u = __float_as_uint(x);
    unsigned r = u + 0x7FFFu + ((u >> 16) & 1u);
    return (unsigned short)(r >> 16);
}

static __device__ __forceinline__ unsigned cvt_pk_bf16(float lo, float hi) {
    unsigned r;
    asm("v_cvt_pk_bf16_f32 %0, %1, %2" : "=v"(r) : "v"(lo), "v"(hi));
    return r;
}

static __device__ __forceinline__ unsigned pk_f16(float lo, float hi) {
    H2U v; v.h[0] = (_Float16)lo; v.h[1] = (_Float16)hi;
    return v.u;
}

// ---------------- prep: fp16 weights (FULL tier) ----------------
__global__ __launch_bounds__(256) void prep_w16(
    const float* __restrict__ weight, const float* __restrict__ w_om,
    _Float16* __restrict__ wt3, _Float16* __restrict__ wmtA)
{
    int t = blockIdx.x * 256 + threadIdx.x;
    if (t < WT3_ELEMS) {
        int i = t & 7;  int u = t >> 3;
        int o = u & 63; u >>= 6;
        int quad = u & 3; u >>= 2;
        int ks = u % 3, kk = u / 3;
        int c = ks * 32 + quad * 8 + i;
        float v = (c < 66) ? weight[o * 594 + c * 9 + kk] : 0.0f;
        wt3[t] = (_Float16)v;
    } else if (t < WT3_ELEMS + WMTA_ELEMS) {
        int t2 = t - WT3_ELEMS;
        int i = t2 & 7;  int u = t2 >> 3;
        int m15 = u & 15; u >>= 4;
        int quad = u & 3; u >>= 2;
        int n = u & 1;    int kt = u >> 1;
        int o = 16 * n + m15;
        float v = 0.0f;
        if (o < 27) {
            if (kt < 18) {
                int j = kt >> 1, c = (kt & 1) * 32 + quad * 8 + i;
                v = w_om[o * 594 + c * 9 + j];
            } else {
                int q = quad * 8 + i;
                if (q < 18) {
                    int j = q >> 1, c = 64 + (q & 1);
                    v = w_om[o * 594 + c * 9 + j];
                }
            }
        }
        wmtA[t2] = (_Float16)v;
    }
}

// ---------------- prep: NCHW fp32 -> NHWC fp16 transpose (vectorized) -------
__global__ __launch_bounds__(256) void prep_t(
    const float* __restrict__ in, _Float16* __restrict__ t_out)
{
    __shared__ float s[64][129];
    const int y = blockIdx.x, b = blockIdx.y;
    const int tid = threadIdx.x, lane = tid & 63, w = tid >> 6;
    const float* src = in + (size_t)b * 64 * HW + y * 128;
#pragma unroll
    for (int i = 0; i < 16; ++i) {
        int c = w * 16 + i;
        s[c][lane]      = src[(size_t)c * HW + lane];
        s[c][lane + 64] = src[(size_t)c * HW + lane + 64];
    }
    __syncthreads();
    _Float16* dst = t_out + ((size_t)b * HW + (size_t)y * 128) * 64;
#pragma unroll
    for (int it = 0; it < 4; ++it) {
        int idx = it * 256 + tid;        // 0..1023
        int x = idx >> 3, g = idx & 7;   // pixel x, channel-group g
        V16 v;
#pragma unroll
        for (int j = 0; j < 8; ++j)
            v.h[j] = (_Float16)s[g * 8 + j][x];
        *(uintx4*)&dst[(size_t)x * 64 + g * 8] = v.u;
    }
}

// ---------------- prep: weights (bf16+fp32, MID tier) ----------------
__global__ __launch_bounds__(256) void prep_w(
    const float* __restrict__ weight, const float* __restrict__ w_om,
    unsigned short* __restrict__ wt3, float* __restrict__ wmt)
{
    int t = blockIdx.x * 256 + threadIdx.x;
    if (t < WT3_ELEMS) {
        int i = t & 7;  int u = t >> 3;
        int o = u & 63; u >>= 6;
        int quad = u & 3; u >>= 2;
        int ks = u % 3, kk = u / 3;
        int c = ks * 32 + quad * 8 + i;
        float v = (c < 66) ? weight[o * 594 + c * 9 + kk] : 0.0f;
        wt3[t] = f2bf(v);
    } else if (t < WT3_ELEMS + WMT_ELEMS) {
        int t2 = t - WT3_ELEMS;
        int oc = t2 % 27, ck = t2 / 27;
        wmt[t2] = w_om[oc * 594 + ck];
    }
}

// Round 2:  XCD-pinning remap (FETCH 268->18.5MB, verified).
// Round 6:  NHWC fp16 shadow input (274 -> 214us).
// Round 7:  Phase A on matrix cores (214 -> 171us).
// Round 10: spill fix (171 -> 119.6us).
// Round 13: LDS gather tile (119.6 -> 69.2us).
// Round 15: LDS overlay -> 3 blocks/CU, occupancy 19.7->27% (69 -> 62.4us).
// Round 16: DEDUPE THE CTX VALU. The 4 lanes of a pixel (m15, m15+16,
//   m15+32, m15+48 of ONE wave) compute identical per-tap ctx (~85 VALU
//   ops each). Now lane (m15,quad) computes ctx for taps t==quad (mod 4)
//   only, packs {fp16 weight pairs, 16b tile-index bases + chunk bits,
//   intile flag, r/c fields} into 6 u32, and per tap all lanes fetch via
//   6 intra-wave ds_bpermute (no barriers). Saves ~510 VALU ops/lane
//   (~40% of VALU) for +~27 LDS-pipe ops. Fallback (!__all(intile))
//   recomputes locally (rare; correctness for arbitrary offsets kept).
__global__ __launch_bounds__(256, 2) void dcn_hybrid15(
    const _Float16* __restrict__ t_in,
    const _Float16* __restrict__ wt3h,
    const _Float16* __restrict__ wmtA,
    const float* __restrict__ bias,
    const float* __restrict__ b_om,
    float* __restrict__ out)
{
    __shared__ __align__(16) unsigned short s_tile[5 * 68 * 64];   // 43520 B
    __shared__ __align__(16) float s_buf[27 * 65];                 // 7020 B

    _Float16* s_offh16 = (_Float16*)s_buf;          // [0,   1152) B
    _Float16* s_offw16 = (_Float16*)s_buf + 576;    // [1152,2304) B
    _Float16* s_mask16 = (_Float16*)s_buf + 1152;   // [2304,3456) B

    const int tid  = threadIdx.x;
    const int lane = tid & 63;
    const int w    = tid >> 6;
    const int wu   = __builtin_amdgcn_readfirstlane(w);
    const int m15  = lane & 15;
    const int quad = lane >> 4;

    // ---- XCD-pinning remap
    const int L   = blockIdx.x + 2 * (blockIdx.y + 128 * blockIdx.z);
    const int b   = L & 7;
    const int r   = L >> 3;
    const int ho  = r >> 1;
    const int wo0 = (r & 1) * 64;

    const float invH = 1.0f / 128.0f;

    const int pixL = wu * 16 + m15;
    const int wob  = wo0 + pixL;

    const _Float16* tinb = t_in + (size_t)b * HW * 64;
    const _Float16* tinq = tinb + quad * 8;     // global-fallback base

    // ---------------- stage the tile (coalesced, once) ----------------
    for (int Lt = tid; Lt < 340; Lt += 256) {
        int rt = Lt / 68, ct = Lt - rt * 68;
        int gy = min(max(ho - 2 + rt, 0), 127);
        int gx = min(max(wo0 - 2 + ct, 0), 127);
        const uintx4* src = (const uintx4*)(tinb + ((size_t)gy * 128 + gx) * 64);
        uintx4* dst = (uintx4*)&s_tile[(size_t)Lt * 64];
        int sw = ct & 7;
#pragma unroll
        for (int k = 0; k < 8; ++k)
            dst[k ^ sw] = src[k];
    }

    auto tidx = [&](int rt, int ct, int q) -> int {
        return (((rt * 68 + ct) << 3) + (q ^ (ct & 7))) << 3;
    };
    auto tld = [&](int i) -> uintx4 {
        return *(const uintx4*)&s_tile[i];
    };

    // ---- 9 fixed-tap tile coords / validity for pixel (ho, wob)
    int   tr9[9], tc9[9];
    float ok9[9];
#pragma unroll
    for (int j = 0; j < 9; ++j) {
        int y = ho - 1 + j / 3;
        int x = wob - 1 + j % 3;
        bool ok = ((unsigned)y < 128u) && ((unsigned)x < 128u);
        int yc = min(max(y, 0), 127), xc = min(max(x, 0), 127);
        tr9[j] = yc - (ho - 2);
        tc9[j] = xc - (wo0 - 2);
        ok9[j] = ok ? 1.0f : 0.0f;
    }
    __syncthreads();   // tile staged

    // ---------------- Phase A: offset conv via f16 MFMA (tile reads) ------
    floatx4 a0 = (floatx4){0.f, 0.f, 0.f, 0.f};
    floatx4 a1 = (floatx4){0.f, 0.f, 0.f, 0.f};

#pragma unroll
    for (int j = 0; j < 9; ++j) {
        _Float16 okh = (_Float16)ok9[j];
        half2v okh2 = {okh, okh};
        int i0 = tidx(tr9[j], tc9[j], quad);
        V16 bbA, bbB;
        bbA.u = tld(i0);
        bbB.u = tld(i0 ^ 32);
#pragma unroll
        for (int rr = 0; rr < 4; ++rr) {
            bbA.h2[rr] = bbA.h2[rr] * okh2;
            bbB.h2[rr] = bbB.h2[rr] * okh2;
        }
#pragma unroll
        for (int h = 0; h < 2; ++h) {
            const int kt = j * 2 + h;
            const _Float16* ap = wmtA + (size_t)((kt * 2) * 4 + quad) * 128 + m15 * 8;
            half8v A0 = *(const half8v*)ap;
            half8v A1 = *(const half8v*)(ap + 512);
            a0 = MFMA16(A0, h ? bbB.h8 : bbA.h8, a0);
            a1 = MFMA16(A1, h ? bbB.h8 : bbA.h8, a1);
        }
    }
    {   // coord K-tile (kt=18)
        V16 bb;
#pragma unroll
        for (int rr = 0; rr < 4; ++rr) {
            float ve = 0.f, vo = 0.f;
            int j = quad * 4 + rr;
            if (j < 9) {
                int y = ho - 1 + j / 3;
                int x = wob - 1 + j % 3;
                bool ok = ((unsigned)y < 128u) && ((unsigned)x < 128u);
                ve = ok ? y * invH : 0.f;
                vo = ok ? (x * invH - 0.5f) : 0.f;
            }
            bb.h2[rr] = (half2v){(_Float16)ve, (_Float16)vo};
        }
        const _Float16* ap = wmtA + (size_t)((18 * 2) * 4 + quad) * 128 + m15 * 8;
        half8v A0 = *(const half8v*)ap;
        half8v A1 = *(const half8v*)(ap + 512);
        a0 = MFMA16(A0, bb.h8, a0);
        a1 = MFMA16(A1, bb.h8, a1);
    }

    // stage om to LDS: s_buf[oc][pix] fp32 (27 rows)
#pragma unroll
    for (int rr = 0; rr < 4; ++rr) {
        s_buf[(quad * 4 + rr) * 65 + pixL] = a0[rr];
        if (quad * 4 + rr < 11)
            s_buf[(16 + quad * 4 + rr) * 65 + pixL] = a1[rr];
    }
    __syncthreads();

    // ---- idx/mask epilogue: read om to regs, barrier, aliased fp16 write
    {
        float* out_idx = out + (size_t)8 * 64 * HW;
        float* out_msk = out_idx + (size_t)8 * 18 * HW;
        const int wo = wo0 + lane;
        const int p  = ho * 128 + wo;
        const float hg = ho * invH;
        const float wg = wo * invH - 0.5f;
        int oc0 = wu * 7;
        int noc = (wu == 3) ? 6 : 7;
        float sv[7];
        for (int t = 0; t < noc; ++t)
            sv[t] = s_buf[(oc0 + t) * 65 + lane];
        __syncthreads();
        for (int t = 0; t < noc; ++t) {
            int oc = oc0 + t;
            float s = b_om[oc] + sv[t];
            if (oc < 9) {
                __builtin_nontemporal_store(hg + (float)(oc / 3 - 1) + s,
                    &out_idx[((size_t)b * 18 + oc) * HW + p]);
                if (oc & 1) s_offw16[(oc >> 1) * 64 + lane] = (_Float16)s;
                else        s_offh16[(oc >> 1) * 64 + lane] = (_Float16)s;
            } else if (oc < 18) {
                __builtin_nontemporal_store(wg + (float)((oc - 9) % 3 - 1) + s,
                    &out_idx[((size_t)b * 18 + oc) * HW + p]);
                if (oc & 1) s_offw16[(oc >> 1) * 64 + lane] = (_Float16)s;
                else        s_offh16[(oc >> 1) * 64 + lane] = (_Float16)s;
            } else {
                float mkv = 1.0f / (1.0f + __expf(-s));
                __builtin_nontemporal_store(mkv,
                    &out_msk[((size_t)b * 9 + (oc - 18)) * HW + p]);
                s_mask16[(oc - 18) * 64 + lane] = (_Float16)mkv;
            }
        }
    }
    __syncthreads();   // offs/mask ready

    // ---------------- ctx producers: this lane covers taps == quad (mod 4)
    // packed ctx (6 u32): [0] w00|w01 fp16  [1] w10|w11 fp16
    // [2] base00(16) | cw00<<16 | intile<<19 | r0<<20 | r1<<23
    // [3] base01 | cw01<<16 | c0<<19   [4] base10 | cw10<<16 | c1<<19
    // [5] base11 | cw11<<16
    unsigned C0[6], C1[6], C2[6];
    const int hom1 = ho - 1;

    auto mk_ctx = [&](int t, unsigned* C) {
        float offh = (float)s_offh16[t * 64 + pixL];
        float offw = (float)s_offw16[t * 64 + pixL];
        float mval = (float)s_mask16[t * 64 + pixL];
        int tdh = (t >= 6) ? 2 : ((t >= 3) ? 1 : 0);
        int tdw = t - 3 * tdh;
        float ph = offh + (float)tdh + (float)hom1;
        float pw = offw + (float)tdw + (float)(wob - 1);
        float h0f = floorf(ph), w0f = floorf(pw);
        int h0 = (int)h0f, w0 = (int)w0f;
        int h1 = h0 + 1, w1 = w0 + 1;
        float lh = ph - h0f, lw = pw - w0f;
        float hh = 1.0f - lh, hwp = 1.0f - lw;
        bool okh0 = (unsigned)h0 < 128u, okh1 = (unsigned)h1 < 128u;
        bool okw0 = (unsigned)w0 < 128u, okw1 = (unsigned)w1 < 128u;
        float w00 = (okh0 && okw0) ? hh * hwp * mval : 0.0f;
        float w01 = (okh0 && okw1) ? hh * lw  * mval : 0.0f;
        float w10 = (okh1 && okw0) ? lh * hwp * mval : 0.0f;
        float w11 = (okh1 && okw1) ? lh * lw  * mval : 0.0f;
        int h0c = min(max(h0, 0), 127), h1c = min(max(h1, 0), 127);
        int w0c = min(max(w0, 0), 127), w1c = min(max(w1, 0), 127);
        int r0 = h0c - (ho - 2), r1 = h1c - (ho - 2);
        int c0 = w0c - (wo0 - 2), c1 = w1c - (wo0 - 2);
        unsigned it = (((unsigned)r0 < 5u) && ((unsigned)r1 < 5u)
                    && ((unsigned)c0 < 68u) && ((unsigned)c1 < 68u)) ? 1u : 0u;
        C[0] = pk_f16(w00, w01);
        C[1] = pk_f16(w10, w11);
        unsigned b00 = ((unsigned)(r0 * 68 + c0) << 6) & 0xFFFFu;
        unsigned b01 = ((unsigned)(r0 * 68 + c1) << 6) & 0xFFFFu;
        unsigned b10 = ((unsigned)(r1 * 68 + c0) << 6) & 0xFFFFu;
        unsigned b11 = ((unsigned)(r1 * 68 + c1) << 6) & 0xFFFFu;
        C[2] = b00 | ((unsigned)(c0 & 7) << 16) | (it << 19)
             | ((unsigned)(r0 & 7) << 20) | ((unsigned)(r1 & 7) << 23);
        C[3] = b01 | ((unsigned)(c1 & 7) << 16) | ((unsigned)(c0 & 127) << 19);
        C[4] = b10 | ((unsigned)(c0 & 7) << 16) | ((unsigned)(c1 & 127) << 19);
        C[5] = b11 | ((unsigned)(c1 & 7) << 16);
    };

    mk_ctx(quad, C0);
    mk_ctx(quad + 4, C1);
    mk_ctx((quad == 0) ? 8 : quad, C2);

    // ---------------- Phase B: shared-ctx tile ds_reads + f16 MFMA --------
    floatx4 acc[4];
#pragma unroll
    for (int t = 0; t < 4; ++t) acc[t] = (floatx4){0.f, 0.f, 0.f, 0.f};

#pragma unroll
    for (int kk = 0; kk < 9; ++kk) {
        const int srcq = kk & 3;
        const int addr = (m15 + (srcq << 4)) << 2;
        unsigned cw0, cw1, K00, K01, K10, K11;
        if (kk < 4) {
            cw0 = __builtin_amdgcn_ds_bpermute(addr, (int)C0[0]);
            cw1 = __builtin_amdgcn_ds_bpermute(addr, (int)C0[1]);
            K00 = __builtin_amdgcn_ds_bpermute(addr, (int)C0[2]);
            K01 = __builtin_amdgcn_ds_bpermute(addr, (int)C0[3]);
            K10 = __builtin_amdgcn_ds_bpermute(addr, (int)C0[4]);
            K11 = __builtin_amdgcn_ds_bpermute(addr, (int)C0[5]);
        } else if (kk < 8) {
            cw0 = __builtin_amdgcn_ds_bpermute(addr, (int)C1[0]);
            cw1 = __builtin_amdgcn_ds_bpermute(addr, (int)C1[1]);
            K00 = __builtin_amdgcn_ds_bpermute(addr, (int)C1[2]);
            K01 = __builtin_amdgcn_ds_bpermute(addr, (int)C1[3]);
            K10 = __builtin_amdgcn_ds_bpermute(addr, (int)C1[4]);
            K11 = __builtin_amdgcn_ds_bpermute(addr, (int)C1[5]);
        } else {
            cw0 = __builtin_amdgcn_ds_bpermute(addr, (int)C2[0]);
            cw1 = __builtin_amdgcn_ds_bpermute(addr, (int)C2[1]);
            K00 = __builtin_amdgcn_ds_bpermute(addr, (int)C2[2]);
            K01 = __builtin_amdgcn_ds_bpermute(addr, (int)C2[3]);
            K10 = __builtin_amdgcn_ds_bpermute(addr, (int)C2[4]);
            K11 = __builtin_amdgcn_ds_bpermute(addr, (int)C2[5]);
        }

        bool it = (K00 >> 19) & 1u;
        V16 A00, A01, A10, A11, B00, B01, B10, B11;
        H2U wab, wcd;
        float w00f, w01f, w10f, w11f;
        int h0c, h1c, w0c, w1c;

        if (__all(it)) {
            int i00 = (int)(K00 & 0xFFFFu) + ((quad ^ (int)((K00 >> 16) & 7)) << 3);
            int i01 = (int)(K01 & 0xFFFFu) + ((quad ^ (int)((K01 >> 16) & 7)) << 3);
            int i10 = (int)(K10 & 0xFFFFu) + ((quad ^ (int)((K10 >> 16) & 7)) << 3);
            int i11 = (int)(K11 & 0xFFFFu) + ((quad ^ (int)((K11 >> 16) & 7)) << 3);
            A00.u = tld(i00);      A01.u = tld(i01);
            A10.u = tld(i10);      A11.u = tld(i11);
            B00.u = tld(i00 ^ 32); B01.u = tld(i01 ^ 32);
            B10.u = tld(i10 ^ 32); B11.u = tld(i11 ^ 32);
            wab.u = cw0; wcd.u = cw1;
            w00f = (float)wab.h[0]; w01f = (float)wab.h[1];
            w10f = (float)wcd.h[0]; w11f = (float)wcd.h[1];
            int r0 = (int)((K00 >> 20) & 7), r1 = (int)((K00 >> 23) & 7);
            int c0 = (int)((K01 >> 19) & 127), c1 = (int)((K10 >> 19) & 127);
            h0c = (ho - 2) + r0; h1c = (ho - 2) + r1;
            w0c = (wo0 - 2) + c0; w1c = (wo0 - 2) + c1;
        } else {
            // rare fallback: full local recompute + global gathers
            float offh = (float)s_offh16[kk * 64 + pixL];
            float offw = (float)s_offw16[kk * 64 + pixL];
            float mval = (float)s_mask16[kk * 64 + pixL];
            float ph = offh + (float)(kk / 3) + (float)hom1;
            float pw = offw + (float)(kk % 3) + (float)(wob - 1);
            float h0f = floorf(ph), w0f = floorf(pw);
            int h0 = (int)h0f, w0 = (int)w0f;
            int h1 = h0 + 1, w1 = w0 + 1;
            float lh = ph - h0f, lw = pw - w0f;
            float hh = 1.0f - lh, hwp = 1.0f - lw;
            bool okh0 = (unsigned)h0 < 128u, okh1 = (unsigned)h1 < 128u;
            bool okw0 = (unsigned)w0 < 128u, okw1 = (unsigned)w1 < 128u;
            w00f = (okh0 && okw0) ? hh * hwp * mval : 0.0f;
            w01f = (okh0 && okw1) ? hh * lw  * mval : 0.0f;
            w10f = (okh1 && okw0) ? lh * hwp * mval : 0.0f;
            w11f = (okh1 && okw1) ? lh * lw  * mval : 0.0f;
            h0c = min(max(h0, 0), 127); h1c = min(max(h1, 0), 127);
            w0c = min(max(w0, 0), 127); w1c = min(max(w1, 0), 127);
            int o00 = h0c * 128 + w0c, o01 = h0c * 128 + w1c;
            int o10 = h1c * 128 + w0c, o11 = h1c * 128 + w1c;
            A00.u = *(const uintx4*)(tinq + (size_t)o00 * 64);
            A01.u = *(const uintx4*)(tinq + (size_t)o01 * 64);
            A10.u = *(const uintx4*)(tinq + (size_t)o10 * 64);
            A11.u = *(const uintx4*)(tinq + (size_t)o11 * 64);
            B00.u = *(const uintx4*)(tinq + (size_t)o00 * 64 + 32);
            B01.u = *(const uintx4*)(tinq + (size_t)o01 * 64 + 32);
            B10.u = *(const uintx4*)(tinq + (size_t)o10 * 64 + 32);
            B11.u = *(const uintx4*)(tinq + (size_t)o11 * 64 + 32);
            wab.u = pk_f16(w00f, w01f);
            wcd.u = pk_f16(w10f, w11f);
        }

        half2v W00 = {wab.h[0], wab.h[0]}, W01 = {wab.h[1], wab.h[1]};
        half2v W10 = {wcd.h[0], wcd.h[0]}, W11 = {wcd.h[1], wcd.h[1]};

        V16 b0, b1, b2;
#pragma unroll
        for (int rr = 0; rr < 4; ++rr) {
            b0.h2[rr] = A00.h2[rr] * W00 + A01.h2[rr] * W01
                      + A10.h2[rr] * W10 + A11.h2[rr] * W11;
            b1.h2[rr] = B00.h2[rr] * W00 + B01.h2[rr] * W01
                      + B10.h2[rr] * W10 + B11.h2[rr] * W11;
        }
        float c64 = (w00f + w01f) * (h0c * invH) + (w10f + w11f) * (h1c * invH);
        float c65 = (w00f + w10f) * (w0c * invH - 0.5f) + (w01f + w11f) * (w1c * invH - 0.5f);
        b2.u = (uintx4){0u, 0u, 0u, 0u};
        if (quad == 0) b2.h2[0] = (half2v){(_Float16)c64, (_Float16)c65};

        const _Float16* w0p = wt3h + (size_t)(kk * 3) * 2048 + quad * 512;
        const _Float16* w1p = w0p + 2048;
        const _Float16* w2p = w0p + 4096;
#pragma unroll
        for (int t = 0; t < 4; ++t) {
            int o8 = (16 * t + m15) * 8;
            half8v A0 = *(const half8v*)&w0p[o8];
            half8v A1 = *(const half8v*)&w1p[o8];
            half8v A2 = *(const half8v*)&w2p[o8];
            acc[t] = MFMA16(A0, b0.h8, acc[t]);
            acc[t] = MFMA16(A1, b1.h8, acc[t]);
            acc[t] = MFMA16(A2, b2.h8, acc[t]);
        }
    }

    // ---------- epilogue: LDS redistribute (4 x 16 ch) -> full-line nt stores
    {
        const size_t rowbase = (size_t)b * 64 * HW + (size_t)ho * 128 + wo0;
#pragma unroll
        for (int t = 0; t < 4; ++t) {
            __syncthreads();
#pragma unroll
            for (int rr = 0; rr < 4; ++rr)
                s_buf[(quad * 4 + rr) * 65 + pixL] = acc[t][rr];
            __syncthreads();
#pragma unroll
            for (int k = 0; k < 4; ++k) {
                int o = 16 * t + wu * 4 + k;
                float v = s_buf[(wu * 4 + k) * 65 + lane] + bias[o];
                __builtin_nontemporal_store(v, &out[(size_t)o * HW + rowbase + lane]);
            }
        }
    }
}

// ---------------- MID tier: R5 kernel (verified), bf16 MFMA ----------------
__global__ __launch_bounds__(256, 4) void dcn_hybrid7(
    const float* __restrict__ input,
    const unsigned short* __restrict__ wt3,
    const float* __restrict__ bias,
    const float* __restrict__ wmt,
    const float* __restrict__ b_om,
    float* __restrict__ out)
{
    __shared__ float s_red[4 * 27 * 64];
    __shared__ float s_offh[9 * 64], s_offw[9 * 64], s_maskf[9 * 64];

    const int tid  = threadIdx.x;
    const int lane = tid & 63;
    const int w    = tid >> 6;
    const int wu   = __builtin_amdgcn_readfirstlane(w);
    const int m15  = lane & 15;
    const int quad = lane >> 4;

    const int L   = blockIdx.x + 2 * (blockIdx.y + 128 * blockIdx.z);
    const int b   = L & 7;
    const int r   = L >> 3;
    const int ho  = r >> 1;
    const int wo0 = (r & 1) * 64;

    const int wo  = wo0 + lane;
    const int p   = ho * 128 + wo;
    const float invH = 1.0f / 128.0f;

    const float* inb = input + (size_t)b * 64 * HW;

    int   a9[9];
    float okf[9], vy[9], vx[9];
#pragma unroll
    for (int j = 0; j < 9; ++j) {
        int y = ho - 1 + j / 3;
        int x = wo - 1 + j % 3;
        bool ok = ((unsigned)y < 128u) && ((unsigned)x < 128u);
        int yc = min(max(y, 0), 127), xc = min(max(x, 0), 127);
        a9[j]  = yc * 128 + xc;
        okf[j] = ok ? 1.0f : 0.0f;
        vy[j]  = ok ? y * invH : 0.0f;
        vx[j]  = ok ? (x * invH - 0.5f) : 0.0f;
    }

    const int nc = (wu < 2) ? 17 : 16;

    float om_part[27];
#pragma unroll
    for (int oc = 0; oc < 27; ++oc) om_part[oc] = 0.0f;

    {
        float va[9], vb[9];
        {
            const float* pc = inb + wu * HW;
#pragma unroll
            for (int j = 0; j < 9; ++j) va[j] = pc[a9[j]] * okf[j];
        }
        for (int i = 0; i < nc; ++i) {
            int c = wu + 4 * i;
            if (i + 1 < nc) {
                int cn = c + 4;
                if (cn < 64) {
                    const float* pc = inb + cn * HW;
#pragma unroll
                    for (int j = 0; j < 9; ++j) vb[j] = pc[a9[j]] * okf[j];
                } else if (cn == 64) {
#pragma unroll
                    for (int j = 0; j < 9; ++j) vb[j] = vy[j];
                } else {
#pragma unroll
                    for (int j = 0; j < 9; ++j) vb[j] = vx[j];
                }
            }
#pragma unroll
            for (int j = 0; j < 9; ++j) {
                const float* wp = wmt + (c * 9 + j) * 27;
#pragma unroll
                for (int oc = 0; oc < 27; ++oc)
                    om_part[oc] = fmaf(va[j], wp[oc], om_part[oc]);
            }
#pragma unroll
            for (int j = 0; j < 9; ++j) va[j] = vb[j];
        }
    }
#pragma unroll
    for (int oc = 0; oc < 27; ++oc)
        s_red[(w * 27 + oc) * 64 + lane] = om_part[oc];
    __syncthreads();

    {
        float* out_idx = out + (size_t)8 * 64 * HW;
        float* out_msk = out_idx + (size_t)8 * 18 * HW;
        const float hg = ho * invH;
        const float wg = wo * invH - 0.5f;
        int oc0 = wu * 7;
        int noc = (wu == 3) ? 6 : 7;
        for (int t = 0; t < noc; ++t) {
            int oc = oc0 + t;
            float s = b_om[oc]
                    + s_red[(0 * 27 + oc) * 64 + lane]
                    + s_red[(1 * 27 + oc) * 64 + lane]
                    + s_red[(2 * 27 + oc) * 64 + lane]
                    + s_red[(3 * 27 + oc) * 64 + lane];
            if (oc < 9) {
                out_idx[((size_t)b * 18 + oc) * HW + p] = hg + (float)(oc / 3 - 1) + s;
                if (oc & 1) s_offw[(oc >> 1) * 64 + lane] = s;
                else        s_offh[(oc >> 1) * 64 + lane] = s;
            } else if (oc < 18) {
                out_idx[((size_t)b * 18 + oc) * HW + p] = wg + (float)((oc - 9) % 3 - 1) + s;
                if (oc & 1) s_offw[(oc >> 1) * 64 + lane] = s;
                else        s_offh[(oc >> 1) * 64 + lane] = s;
            } else {
                float mkv = 1.0f / (1.0f + __expf(-s));
                out_msk[((size_t)b * 9 + (oc - 18)) * HW + p] = mkv;
                s_maskf[(oc - 18) * 64 + lane] = mkv;
            }
        }
    }
    __syncthreads();

    const int pixL = wu * 16 + m15;
    const int wob  = wo0 + pixL;
    const int hom1 = ho - 1;

    floatx4 acc[4];
#pragma unroll
    for (int t = 0; t < 4; ++t) acc[t] = (floatx4){0.f, 0.f, 0.f, 0.f};

    const float* base0 = inb + (size_t)(quad * 8) * HW;
    const float* base1 = base0 + (size_t)32 * HW;

#pragma unroll
    for (int kk = 0; kk < 9; ++kk) {
        float offh = s_offh[kk * 64 + pixL];
        float offw = s_offw[kk * 64 + pixL];
        float mval = s_maskf[kk * 64 + pixL];

        float ph = offh + (float)(kk / 3) + (float)hom1;
        float pw = offw + (float)(kk % 3) + (float)(wob - 1);
        float h0f = floorf(ph), w0f = floorf(pw);
        int h0 = (int)h0f, w0 = (int)w0f;
        int h1 = h0 + 1, w1 = w0 + 1;
        float lh = ph - h0f, lw = pw - w0f;
        float hh = 1.0f - lh, hwp = 1.0f - lw;
        bool okh0 = (unsigned)h0 < 128u, okh1 = (unsigned)h1 < 128u;
        bool okw0 = (unsigned)w0 < 128u, okw1 = (unsigned)w1 < 128u;
        float w00 = (okh0 && okw0) ? hh * hwp * mval : 0.0f;
        float w01 = (okh0 && okw1) ? hh * lw  * mval : 0.0f;
        float w10 = (okh1 && okw0) ? lh * hwp * mval : 0.0f;
        float w11 = (okh1 && okw1) ? lh * lw  * mval : 0.0f;
        int h0c = min(max(h0, 0), 127), h1c = min(max(h1, 0), 127);
        int w0c = min(max(w0, 0), 127), w1c = min(max(w1, 0), 127);
        int o00 = h0c * 128 + w0c, o01 = h0c * 128 + w1c;
        int o10 = h1c * 128 + w0c, o11 = h1c * 128 + w1c;

        unsigned pk0[4], pk1[4];
#pragma unroll
        for (int j = 0; j < 4; ++j) {
            const float* pa = base0 + (size_t)(2 * j) * HW;
            const float* pb = pa + HW;
            float ca = w00 * pa[o00] + w01 * pa[o01] + w10 * pa[o10] + w11 * pa[o11];
            float cb = w00 * pb[o00] + w01 * pb[o01] + w10 * pb[o10] + w11 * pb[o11];
            pk0[j] = cvt_pk_bf16(ca, cb);
            const float* pa1 = base1 + (size_t)(2 * j) * HW;
            const float* pb1 = pa1 + HW;
            float ca1 = w00 * pa1[o00] + w01 * pa1[o01] + w10 * pa1[o10] + w11 * pa1[o11];
            float cb1 = w00 * pb1[o00] + w01 * pb1[o01] + w10 * pb1[o10] + w11 * pb1[o11];
            pk1[j] = cvt_pk_bf16(ca1, cb1);
        }
        union { uintx4 u; short8 s; } b0, b1, b2;
        b0.u = (uintx4){pk0[0], pk0[1], pk0[2], pk0[3]};
        b1.u = (uintx4){pk1[0], pk1[1], pk1[2], pk1[3]};
        float c64 = (w00 + w01) * (h0c * invH) + (w10 + w11) * (h1c * invH);
        float c65 = (w00 + w10) * (w0c * invH - 0.5f) + (w01 + w11) * (w1c * invH - 0.5f);
        unsigned pk2 = (quad == 0) ? cvt_pk_bf16(c64, c65) : 0u;
        b2.u = (uintx4){pk2, 0u, 0u, 0u};

        const unsigned short* w0p = wt3 + (size_t)(kk * 3 + 0) * 2048 + quad * 512;
        const unsigned short* w1p = w0p + 2048;
        const unsigned short* w2p = w0p + 4096;
#pragma unroll
        for (int t = 0; t < 4; ++t) {
            int o8 = (16 * t + m15) * 8;
            short8 A0 = *(const short8*)&w0p[o8];
            short8 A1 = *(const short8*)&w1p[o8];
            short8 A2 = *(const short8*)&w2p[o8];
            acc[t] = MFMA(A0, b0.s, acc[t]);
            acc[t] = MFMA(A1, b1.s, acc[t]);
            acc[t] = MFMA(A2, b2.s, acc[t]);
        }
    }

    {
        size_t pb = (size_t)ho * 128 + wob;
#pragma unroll
        for (int t = 0; t < 4; ++t) {
#pragma unroll
            for (int rr = 0; rr < 4; ++rr) {
                int o = 16 * t + quad * 4 + rr;
                out[((size_t)b * 64 + o) * HW + pb] = acc[t][rr] + bias[o];
            }
        }
    }
}

// ------------------- fallback (no workspace): fp32 baseline -------------------
__global__ __launch_bounds__(256) void dcn_fb(
    const float* __restrict__ input,
    const float* __restrict__ wmain,
    const float* __restrict__ bias,
    const float* __restrict__ wom,
    const float* __restrict__ b_om,
    float* __restrict__ out)
{
    const int wo = blockIdx.x * 64 + threadIdx.x;
    const int ho = blockIdx.y * 4 + threadIdx.y;
    const int b  = blockIdx.z;
    const int p  = ho * 128 + wo;
    const float invH = 1.0f / 128.0f;
    const float* inb = input + (size_t)b * 64 * HW;

    float om[27];
#pragma unroll
    for (int oc = 0; oc < 27; ++oc) om[oc] = b_om[oc];

    for (int c = 0; c < 64; ++c) {
        const float* pc = inb + c * HW;
        float v[9];
#pragma unroll
        for (int kh = 0; kh < 3; ++kh) {
            int y = ho - 1 + kh;
            bool oky = (unsigned)y < 128u;
#pragma unroll
            for (int kw = 0; kw < 3; ++kw) {
                int x = wo - 1 + kw;
                bool ok = oky && ((unsigned)x < 128u);
                v[kh*3+kw] = ok ? pc[y * 128 + x] : 0.0f;
            }
        }
#pragma unroll
        for (int oc = 0; oc < 27; ++oc)
#pragma unroll
            for (int i = 0; i < 9; ++i)
                om[oc] = fmaf(v[i], wom[oc*594 + c*9 + i], om[oc]);
    }
    {
        float v64[9], v65[9];
#pragma unroll
        for (int kh = 0; kh < 3; ++kh) {
            int y = ho - 1 + kh;
            bool oky = (unsigned)y < 128u;
#pragma unroll
            for (int kw = 0; kw < 3; ++kw) {
                int x = wo - 1 + kw;
                bool ok = oky && ((unsigned)x < 128u);
                v64[kh*3+kw] = ok ? y * invH : 0.0f;
                v65[kh*3+kw] = ok ? (x * invH - 0.5f) : 0.0f;
            }
        }
#pragma unroll
        for (int oc = 0; oc < 27; ++oc)
#pragma unroll
            for (int i = 0; i < 9; ++i) {
                om[oc] = fmaf(v64[i], wom[oc*594 + 64*9 + i], om[oc]);
                om[oc] = fmaf(v65[i], wom[oc*594 + 65*9 + i], om[oc]);
            }
    }

    const float hg = ho * invH;
    const float wg = wo * invH - 0.5f;
    float* out_idx = out + (size_t)8 * 64 * HW;
    float* out_msk = out_idx + (size_t)8 * 18 * HW;
#pragma unroll
    for (int cc = 0; cc < 9; ++cc)
        out_idx[((size_t)b*18 + cc)*HW + p] = hg + (float)(cc/3 - 1) + om[cc];
#pragma unroll
    for (int cc = 9; cc < 18; ++cc)
        out_idx[((size_t)b*18 + cc)*HW + p] = wg + (float)((cc-9)%3 - 1) + om[cc];

    float mk[9];
#pragma unroll
    for (int kk = 0; kk < 9; ++kk) {
        mk[kk] = 1.0f / (1.0f + __expf(-om[18+kk]));
        out_msk[((size_t)b*9 + kk)*HW + p] = mk[kk];
    }

    float acc[64];
#pragma unroll
    for (int o = 0; o < 64; ++o) acc[o] = bias[o];

#pragma unroll
    for (int kk = 0; kk < 9; ++kk) {
        float ph = om[2*kk]   + (float)(kk/3) + (float)(ho - 1);
        float pw = om[2*kk+1] + (float)(kk%3) + (float)(wo - 1);
        float h0f = floorf(ph), w0f = floorf(pw);
        int h0 = (int)h0f, w0 = (int)w0f;
        int h1 = h0 + 1, w1 = w0 + 1;
        float lh = ph - h0f, lw = pw - w0f;
        float hh = 1.0f - lh, hwp = 1.0f - lw;
        float m = mk[kk];
        bool okh0 = (unsigned)h0 < 128u, okh1 = (unsigned)h1 < 128u;
        bool okw0 = (unsigned)w0 < 128u, okw1 = (unsigned)w1 < 128u;
        float w00 = (okh0 && okw0) ? hh*hwp*m : 0.0f;
        float w01 = (okh0 && okw1) ? hh*lw*m  : 0.0f;
        float w10 = (okh1 && okw0) ? lh*hwp*m : 0.0f;
        float w11 = (okh1 && okw1) ? lh*lw*m  : 0.0f;
        int h0c = min(max(h0, 0), 127), h1c = min(max(h1, 0), 127);
        int w0c = min(max(w0, 0), 127), w1c = min(max(w1, 0), 127);
        int o00 = h0c*128 + w0c, o01 = h0c*128 + w1c;
        int o10 = h1c*128 + w0c, o11 = h1c*128 + w1c;

        for (int c = 0; c < 64; ++c) {
            const float* pc = inb + c * HW;
            float col = w00*pc[o00] + w01*pc[o01] + w10*pc[o10] + w11*pc[o11];
#pragma unroll
            for (int o = 0; o < 64; ++o)
                acc[o] = fmaf(col, wmain[o*594 + c*9 + kk], acc[o]);
        }
        {
            float y0 = h0c * invH, y1 = h1c * invH;
            float x0 = w0c * invH - 0.5f, x1 = w1c * invH - 0.5f;
            float col64 = (w00 + w01)*y0 + (w10 + w11)*y1;
            float col65 = (w00 + w10)*x0 + (w01 + w11)*x1;
#pragma unroll
            for (int o = 0; o < 64; ++o) {
                acc[o] = fmaf(col64, wmain[o*594 + 64*9 + kk], acc[o]);
                acc[o] = fmaf(col65, wmain[o*594 + 65*9 + kk], acc[o]);
            }
        }
    }

#pragma unroll
    for (int o = 0; o < 64; ++o)
        out[((size_t)b*64 + o)*HW + p] = acc[o];
}

extern "C" void kernel_launch(void* const* d_in, const int* in_sizes, int n_in,
                              void* d_out, int out_size, void* d_ws, size_t ws_size,
                              hipStream_t stream)
{
    const float* input  = (const float*)d_in[0];
    const float* weight = (const float*)d_in[1];
    const float* bias   = (const float*)d_in[2];
    const float* w_om   = (const float*)d_in[3];
    const float* b_om   = (const float*)d_in[4];
    float* out = (float*)d_out;

    if (ws_size >= WS_FULL) {
        _Float16* tin  = (_Float16*)d_ws;
        _Float16* wt3h = (_Float16*)((char*)d_ws + WT3_OFF);
        _Float16* wmtA = (_Float16*)((char*)d_ws + WMTA_OFF);
        int total = WT3_ELEMS + WMTA_ELEMS;
        prep_w16<<<(total + 255) / 256, 256, 0, stream>>>(weight, w_om, wt3h, wmtA);
        prep_t<<<dim3(128, 8), 256, 0, stream>>>(input, tin);
        dim3 grid(2, 128, 8);
        dcn_hybrid15<<<grid, dim3(256, 1, 1), 0, stream>>>(tin, wt3h, wmtA, bias, b_om, out);
    } else if (ws_size >= WS_MID) {
        unsigned short* wt3 = (unsigned short*)d_ws;
        float* wmt = (float*)((char*)d_ws + (size_t)WT3_ELEMS * 2);
        int total = WT3_ELEMS + WMT_ELEMS;
        prep_w<<<(total + 255) / 256, 256, 0, stream>>>(weight, w_om, wt3, wmt);
        dim3 grid(2, 128, 8);
        dcn_hybrid7<<<grid, dim3(256, 1, 1), 0, stream>>>(input, wt3, bias, wmt, b_om, out);
    } else {
        dim3 grid(2, 32, 8);
        dcn_fb<<<grid, dim3(64, 4, 1), 0, stream>>>(input, weight, bias, w_om, b_om, out);
    }
}